// Round 5
// baseline (417.529 us; speedup 1.0000x reference)
//
#include <hip/hip_runtime.h>
#include <stdint.h>

#define NROWS 32768

typedef float f32x4 __attribute__((ext_vector_type(4)));
typedef __bf16 bfx8 __attribute__((ext_vector_type(8)));
typedef unsigned uint4v __attribute__((ext_vector_type(4)));

// ---------- helpers ----------
static __device__ __forceinline__ unsigned short f2bf(float f) {
    unsigned u = __builtin_bit_cast(unsigned, f);
    u += 0x7fffu + ((u >> 16) & 1u);   // RNE
    return (unsigned short)(u >> 16);
}

static __device__ __forceinline__ f32x4 mfma16(bfx8 a, bfx8 b, f32x4 c) {
    return __builtin_amdgcn_mfma_f32_16x16x32_bf16(a, b, c, 0, 0, 0);
}

// XOR swizzle of column index (elements, bf16): permutes 16B slots within 8-slot groups
static __device__ __forceinline__ int swz(int row, int col) {
    return col ^ ((row & 7) << 3);
}

// ---------- workspace layout (bytes) ----------
static constexpr size_t A_AUG_B  = 0;            // [32768][640] bf16 = 41,943,040
static constexpr size_t JOINED_B = 41943040;     // [32768][512] bf16 = 33,554,432
static constexpr size_t G1_B     = 75497472;     // [32768][128] bf16 =  8,388,608
static constexpr size_t WCT_B    = 83886080;     // [640][640] bf16   =    819,200
static constexpr size_t SPW2T_B  = 84705280;     // [128][128] bf16   =     32,768
static constexpr size_t SPW3T_B  = 84738048;     //                         32,768
static constexpr size_t VPW2T_B  = 84770816;     //                         32,768
static constexpr size_t VPW3T_B  = 84803584;     // [16][128] bf16    =      4,096
static constexpr size_t C1T_B    = 84807680;     // [4][256][512] bf16=  1,048,576
static constexpr size_t C2T_B    = 85856256;     // [4][256][256] bf16=    524,288
static constexpr size_t C3T_B    = 86380544;     // [4][16][256] bf16 =     32,768
static constexpr size_t CNT_B    = 86413312;     // 16 ints           =         64
static constexpr size_t SORTED_B = 86413376;     // [4][32768] int    =    524,288
static constexpr size_t WS_NEED  = 86937664;

// ---------- K0: weight transpose/convert + counter zero ----------
__global__ __launch_bounds__(256) void k_prep(
    const float* joinW, const float* vpW1, const float* spW2, const float* spW3,
    const float* vpW2, const float* vpW3, const float* c1, const float* c2, const float* c3,
    unsigned short* wct, unsigned short* spw2t, unsigned short* spw3t,
    unsigned short* vpw2t, unsigned short* vpw3t,
    unsigned short* c1t, unsigned short* c2t, unsigned short* c3t, int* cnt)
{
    int bid = blockIdx.x, tid = threadIdx.x;
    if (bid == 0 && tid < 16) cnt[tid] = 0;
    int region, idx0;
    if      (bid < 400)  { region = 0; idx0 = bid * 1024; }
    else if (bid < 416)  { region = 1; idx0 = (bid - 400) * 1024; }
    else if (bid < 432)  { region = 2; idx0 = (bid - 416) * 1024; }
    else if (bid < 448)  { region = 3; idx0 = (bid - 432) * 1024; }
    else if (bid < 450)  { region = 4; idx0 = (bid - 448) * 1024; }
    else if (bid < 962)  { region = 5; idx0 = (bid - 450) * 1024; }
    else if (bid < 1218) { region = 6; idx0 = (bid - 962) * 1024; }
    else                 { region = 7; idx0 = (bid - 1218) * 1024; }
    for (int j = 0; j < 4; ++j) {
        int idx = idx0 + tid + j * 256;
        switch (region) {
        case 0: { // WcT [640 n][640 k]: n<512 join_W[k][n]; n>=512 vp_W1[k][n-512] (k<512) else 0
            int n = idx / 640, k = idx % 640;
            float v = (n < 512) ? joinW[(size_t)k * 512 + n]
                                : (k < 512 ? vpW1[(size_t)k * 128 + (n - 512)] : 0.f);
            wct[idx] = f2bf(v);
        } break;
        case 1: { int n = idx >> 7, k = idx & 127; spw2t[idx] = f2bf(spW2[k * 128 + n]); } break;
        case 2: { int n = idx >> 7, k = idx & 127; spw3t[idx] = f2bf(spW3[k * 128 + n]); } break;
        case 3: { int n = idx >> 7, k = idx & 127; vpw2t[idx] = f2bf(vpW2[k * 128 + n]); } break;
        case 4: { int n = idx >> 7, k = idx & 127; vpw3t[idx] = f2bf(n == 0 ? vpW3[k] : 0.f); } break;
        case 5: { int e = idx >> 17, rem = idx & 131071, n = rem >> 9, k = rem & 511;
                  c1t[idx] = f2bf(c1[(size_t)e * 131072 + k * 256 + n]); } break;
        case 6: { int e = idx >> 16, rem = idx & 65535, n = rem >> 8, k = rem & 255;
                  c2t[idx] = f2bf(c2[(size_t)e * 65536 + k * 256 + n]); } break;
        case 7: { int e = idx >> 12, rem = idx & 4095, n = rem >> 8, k = rem & 255;
                  c3t[idx] = f2bf(n < 3 ? c3[(size_t)e * 768 + k * 3 + n] : 0.f); } break;
        }
    }
}

// ---------- K1: p_i f32->bf16 into A_aug[:,0:512] + sp-MLP -> A_aug[:,512:640] ----------
__global__ __launch_bounds__(256) void k_sp_convert(
    const float* p_i, const float* speed, const float* spW1, const float* spb1,
    const float* spb2, const float* spb3,
    const unsigned short* spw2t, const unsigned short* spw3t, unsigned short* Aaug)
{
    __shared__ alignas(16) unsigned short h1[128 * 128];  // swizzled
    __shared__ alignas(16) unsigned short h2[128 * 128];  // swizzled
    int bid = blockIdx.x, tid = threadIdx.x;
    int r0 = bid * 128;
    // p_i conversion: 128 rows x 512 cols, float4 -> ushort4
#pragma unroll 4
    for (int j = 0; j < 64; ++j) {
        int c = tid + j * 256;                 // 16384 float4 chunks
        int row = c >> 7, col4 = (c & 127) * 4;
        f32x4 v = *(const f32x4*)(p_i + (size_t)(r0 + row) * 512 + col4);
        ushort4 o;
        o.x = f2bf(v.x); o.y = f2bf(v.y); o.z = f2bf(v.z); o.w = f2bf(v.w);
        *(ushort4*)(Aaug + (size_t)(r0 + row) * 640 + col4) = o;
    }
    // h1 = relu(speed*W1 + b1) -> LDS (swizzled)
    for (int j = 0; j < 64; ++j) {
        int idx = tid + j * 256;
        int row = idx >> 7, col = idx & 127;
        float h = speed[r0 + row] * spW1[col] + spb1[col];
        h = h > 0.f ? h : 0.f;
        h1[row * 128 + swz(row, col)] = f2bf(h);
    }
    __syncthreads();

    int wave = tid >> 6, lane = tid & 63, lq = lane >> 4, lr = lane & 15;
    int wr = wave >> 1, wc = wave & 1;
    // GEMM1: h2 = relu(h1 @ spW2T + b2)
    f32x4 acc[4][4] = {};
#pragma unroll
    for (int ks = 0; ks < 4; ++ks) {
        bfx8 a[4], b[4];
#pragma unroll
        for (int mt = 0; mt < 4; ++mt) {
            int row = wr * 64 + mt * 16 + lr;
            a[mt] = *(const bfx8*)&h1[row * 128 + swz(row, ks * 32 + lq * 8)];
        }
#pragma unroll
        for (int nt = 0; nt < 4; ++nt) {
            int n = wc * 64 + nt * 16 + lr;
            b[nt] = *(const bfx8*)(spw2t + n * 128 + ks * 32 + lq * 8);
        }
#pragma unroll
        for (int mt = 0; mt < 4; ++mt)
#pragma unroll
            for (int nt = 0; nt < 4; ++nt)
                acc[mt][nt] = mfma16(a[mt], b[nt], acc[mt][nt]);
    }
#pragma unroll
    for (int mt = 0; mt < 4; ++mt)
#pragma unroll
        for (int nt = 0; nt < 4; ++nt)
#pragma unroll
            for (int j = 0; j < 4; ++j) {
                int row = wr * 64 + mt * 16 + lq * 4 + j;
                int col = wc * 64 + nt * 16 + lr;
                float v = acc[mt][nt][j] + spb2[col];
                v = v > 0.f ? v : 0.f;
                h2[row * 128 + swz(row, col)] = f2bf(v);
            }
    __syncthreads();
    // GEMM2: v = h2 @ spW3T + b3 (no relu) -> A_aug cols 512..639
    f32x4 acc2[4][4] = {};
#pragma unroll
    for (int ks = 0; ks < 4; ++ks) {
        bfx8 a[4], b[4];
#pragma unroll
        for (int mt = 0; mt < 4; ++mt) {
            int row = wr * 64 + mt * 16 + lr;
            a[mt] = *(const bfx8*)&h2[row * 128 + swz(row, ks * 32 + lq * 8)];
        }
#pragma unroll
        for (int nt = 0; nt < 4; ++nt) {
            int n = wc * 64 + nt * 16 + lr;
            b[nt] = *(const bfx8*)(spw3t + n * 128 + ks * 32 + lq * 8);
        }
#pragma unroll
        for (int mt = 0; mt < 4; ++mt)
#pragma unroll
            for (int nt = 0; nt < 4; ++nt)
                acc2[mt][nt] = mfma16(a[mt], b[nt], acc2[mt][nt]);
    }
#pragma unroll
    for (int mt = 0; mt < 4; ++mt)
#pragma unroll
        for (int nt = 0; nt < 4; ++nt)
#pragma unroll
            for (int j = 0; j < 4; ++j) {
                int row = wr * 64 + mt * 16 + lq * 4 + j;
                int col = wc * 64 + nt * 16 + lr;
                Aaug[(size_t)(r0 + row) * 640 + 512 + col] = f2bf(acc2[mt][nt][j] + spb3[col]);
            }
}

// ---------- K_route: bucket rows by command ----------
__global__ __launch_bounds__(256) void k_scatter(const int* command, int* cnt, int* sorted)
{
    __shared__ int lcnt[4], lbase[4];
    int tid = threadIdx.x;
    int r = blockIdx.x * 256 + tid;
    if (tid < 4) lcnt[tid] = 0;
    __syncthreads();
    int c = command[r] & 3;
    int lpos = atomicAdd(&lcnt[c], 1);
    __syncthreads();
    if (tid < 4) lbase[tid] = atomicAdd(&cnt[tid], lcnt[tid]);
    __syncthreads();
    sorted[c * NROWS + lbase[c] + lpos] = r;
}

// ---------- K2: joined+g1 = A_aug @ [join_W | vp_W1_pad]  (128x128 tile MFMA) ----------
__global__ __launch_bounds__(256) void k_join(
    const unsigned short* Aaug, const unsigned short* wct,
    const float* joinb, const float* vpb1, unsigned short* joined, unsigned short* g1)
{
    __shared__ alignas(16) unsigned short At[128 * 64];
    __shared__ alignas(16) unsigned short Bt[128 * 64];
    int d = blockIdx.x;
    int L = (d & 7) * 160 + (d >> 3);       // XCD swizzle (1280 % 8 == 0, bijective)
    int m0 = (L / 5) * 128, n0 = (L % 5) * 128;
    int tid = threadIdx.x, wave = tid >> 6, lane = tid & 63, lq = lane >> 4, lr = lane & 15;
    int wr = wave >> 1, wc = wave & 1;
    f32x4 acc[4][4] = {};
#pragma unroll 1
    for (int kt = 0; kt < 10; ++kt) {
#pragma unroll
        for (int c2 = 0; c2 < 4; ++c2) {
            int chunk = c2 * 256 + tid;       // 1024 chunks of 16B, 8 per 128B row
            int row = chunk >> 3, slot = chunk & 7;
            uint4v va = *(const uint4v*)(Aaug + (size_t)(m0 + row) * 640 + kt * 64 + slot * 8);
            uint4v vb = *(const uint4v*)(wct + (size_t)(n0 + row) * 640 + kt * 64 + slot * 8);
            *(uint4v*)&At[chunk * 8] = va;
            *(uint4v*)&Bt[chunk * 8] = vb;
        }
        __syncthreads();
#pragma unroll
        for (int ks = 0; ks < 2; ++ks) {
            bfx8 a[4], b[4];
#pragma unroll
            for (int mt = 0; mt < 4; ++mt)
                a[mt] = *(const bfx8*)&At[(wr * 64 + mt * 16 + lr) * 64 + ks * 32 + lq * 8];
#pragma unroll
            for (int nt = 0; nt < 4; ++nt)
                b[nt] = *(const bfx8*)&Bt[(wc * 64 + nt * 16 + lr) * 64 + ks * 32 + lq * 8];
#pragma unroll
            for (int mt = 0; mt < 4; ++mt)
#pragma unroll
                for (int nt = 0; nt < 4; ++nt)
                    acc[mt][nt] = mfma16(a[mt], b[nt], acc[mt][nt]);
        }
        __syncthreads();
    }
#pragma unroll
    for (int mt = 0; mt < 4; ++mt)
#pragma unroll
        for (int nt = 0; nt < 4; ++nt)
#pragma unroll
            for (int j = 0; j < 4; ++j) {
                int row = m0 + wr * 64 + mt * 16 + lq * 4 + j;
                int col = n0 + wc * 64 + nt * 16 + lr;
                float v = acc[mt][nt][j];
                if (col < 512) {
                    joined[(size_t)row * 512 + col] = f2bf(v + joinb[col]);
                } else {
                    v += vpb1[col - 512];
                    v = v > 0.f ? v : 0.f;
                    g1[(size_t)row * 128 + (col - 512)] = f2bf(v);
                }
            }
}

// ---------- K3: vp tail: g2 = relu(g1@W2+b2); v_p = g2@W3+b3 -> out[0:B] (f32 out) ----------
__global__ __launch_bounds__(256) void k_vp(
    const unsigned short* g1, const unsigned short* vpw2t, const unsigned short* vpw3t,
    const float* vpb2, const float* vpb3, float* out_vp)
{
    __shared__ alignas(16) unsigned short gt[128 * 128];   // swizzled
    __shared__ alignas(16) unsigned short h2[128 * 128];   // swizzled
    int bid = blockIdx.x, tid = threadIdx.x;
    int r0 = bid * 128;
    // stage g1 tile: read linear global, write swizzled LDS (reg-staged)
#pragma unroll
    for (int c2 = 0; c2 < 8; ++c2) {
        int chunk = c2 * 256 + tid;            // 2048 chunks of 16B, 16 per 256B row
        int row = chunk >> 4, slot = chunk & 15;
        int sslot = slot ^ (row & 7);
        uint4v v = *(const uint4v*)(g1 + (size_t)(r0 + row) * 128 + slot * 8);
        *(uint4v*)&gt[row * 128 + sslot * 8] = v;
    }
    __syncthreads();
    int wave = tid >> 6, lane = tid & 63, lq = lane >> 4, lr = lane & 15;
    int wr = wave >> 1, wc = wave & 1;
    // GEMM1: h2 = relu(gt @ vpW2T + b2)
    f32x4 acc[4][4] = {};
#pragma unroll
    for (int ks = 0; ks < 4; ++ks) {
        bfx8 a[4], b[4];
#pragma unroll
        for (int mt = 0; mt < 4; ++mt) {
            int row = wr * 64 + mt * 16 + lr;
            a[mt] = *(const bfx8*)&gt[row * 128 + swz(row, ks * 32 + lq * 8)];
        }
#pragma unroll
        for (int nt = 0; nt < 4; ++nt) {
            int n = wc * 64 + nt * 16 + lr;
            b[nt] = *(const bfx8*)(vpw2t + n * 128 + ks * 32 + lq * 8);
        }
#pragma unroll
        for (int mt = 0; mt < 4; ++mt)
#pragma unroll
            for (int nt = 0; nt < 4; ++nt)
                acc[mt][nt] = mfma16(a[mt], b[nt], acc[mt][nt]);
    }
#pragma unroll
    for (int mt = 0; mt < 4; ++mt)
#pragma unroll
        for (int nt = 0; nt < 4; ++nt)
#pragma unroll
            for (int j = 0; j < 4; ++j) {
                int row = wr * 64 + mt * 16 + lq * 4 + j;
                int col = wc * 64 + nt * 16 + lr;
                float v = acc[mt][nt][j] + vpb2[col];
                v = v > 0.f ? v : 0.f;
                h2[row * 128 + swz(row, col)] = f2bf(v);
            }
    __syncthreads();
    // GEMM2: v_p = h2 @ vpW3T(pad N=16) + b3; only col 0 valid
    f32x4 acc2[2] = {};
#pragma unroll
    for (int ks = 0; ks < 4; ++ks) {
        bfx8 b = *(const bfx8*)(vpw3t + lr * 128 + ks * 32 + lq * 8);
#pragma unroll
        for (int mt = 0; mt < 2; ++mt) {
            int row = wave * 32 + mt * 16 + lr;
            bfx8 a = *(const bfx8*)&h2[row * 128 + swz(row, ks * 32 + lq * 8)];
            acc2[mt] = mfma16(a, b, acc2[mt]);
        }
    }
    if (lr == 0) {
#pragma unroll
        for (int mt = 0; mt < 2; ++mt)
#pragma unroll
            for (int j = 0; j < 4; ++j) {
                int row = wave * 32 + mt * 16 + lq * 4 + j;
                out_vp[r0 + row] = acc2[mt][j] + vpb3[0];
            }
    }
}

// ---------- K4: routed control heads (each block single-expert, f32 out) ----------
__global__ __launch_bounds__(512) void k_ctrl(
    const unsigned short* joined, const unsigned short* c1t, const unsigned short* c2t,
    const unsigned short* c3t, const float* b1, const float* b2, const float* b3,
    const int* cnt, const int* sorted, float* out_act)
{
    __shared__ alignas(16) unsigned short hbuf[64 * 256];  // swizzled; holds h then h2
    __shared__ int ridx[64];
    int bid = blockIdx.x;
    int e = bid >> 9, i = bid & 511;
    int n_e = cnt[e];
    if (i * 64 >= n_e) return;
    int tid = threadIdx.x;
    if (tid < 64) {
        int g = i * 64 + tid;
        ridx[tid] = sorted[e * NROWS + (g < n_e ? g : n_e - 1)];
    }
    __syncthreads();
    int wave = tid >> 6, lane = tid & 63, lq = lane >> 4, lr = lane & 15;
    int wm = wave & 3, wn = wave >> 2;        // 4M x 2N waves
    const unsigned short* W1 = c1t + e * (256 * 512);
    const unsigned short* W2 = c2t + e * (256 * 256);
    const unsigned short* W3 = c3t + e * (16 * 256);
    // GEMM1: h = relu(joined[rows] @ W1T + b1); A gathered per-lane from global (L2)
    const unsigned short* aptr = joined + (size_t)ridx[wm * 16 + lr] * 512;
    f32x4 acc[8] = {};
#pragma unroll 2
    for (int ks = 0; ks < 16; ++ks) {
        bfx8 a = *(const bfx8*)(aptr + ks * 32 + lq * 8);
#pragma unroll
        for (int nt = 0; nt < 8; ++nt) {
            int n = wn * 128 + nt * 16 + lr;
            bfx8 b = *(const bfx8*)(W1 + n * 512 + ks * 32 + lq * 8);
            acc[nt] = mfma16(a, b, acc[nt]);
        }
    }
#pragma unroll
    for (int nt = 0; nt < 8; ++nt)
#pragma unroll
        for (int j = 0; j < 4; ++j) {
            int row = wm * 16 + lq * 4 + j;
            int col = wn * 128 + nt * 16 + lr;
            float v = acc[nt][j] + b1[e * 256 + col];
            v = v > 0.f ? v : 0.f;
            hbuf[row * 256 + swz(row, col)] = f2bf(v);
        }
    __syncthreads();
    // GEMM2: h2 = relu(h @ W2T + b2)
    f32x4 acc2[8] = {};
#pragma unroll 2
    for (int ks = 0; ks < 8; ++ks) {
        int row = wm * 16 + lr;
        bfx8 a = *(const bfx8*)&hbuf[row * 256 + swz(row, ks * 32 + lq * 8)];
#pragma unroll
        for (int nt = 0; nt < 8; ++nt) {
            int n = wn * 128 + nt * 16 + lr;
            bfx8 b = *(const bfx8*)(W2 + n * 256 + ks * 32 + lq * 8);
            acc2[nt] = mfma16(a, b, acc2[nt]);
        }
    }
    __syncthreads();   // all reads of h done before overwrite
#pragma unroll
    for (int nt = 0; nt < 8; ++nt)
#pragma unroll
        for (int j = 0; j < 4; ++j) {
            int row = wm * 16 + lq * 4 + j;
            int col = wn * 128 + nt * 16 + lr;
            float v = acc2[nt][j] + b2[e * 256 + col];
            v = v > 0.f ? v : 0.f;
            hbuf[row * 256 + swz(row, col)] = f2bf(v);
        }
    __syncthreads();
    // GEMM3: a = h2 @ W3T(pad N=16) + b3; waves wn==0 only; cols 0..2 valid
    if (wn == 0) {
        f32x4 acc3 = {};
#pragma unroll
        for (int ks = 0; ks < 8; ++ks) {
            int row = wm * 16 + lr;
            bfx8 a = *(const bfx8*)&hbuf[row * 256 + swz(row, ks * 32 + lq * 8)];
            bfx8 b = *(const bfx8*)(W3 + lr * 256 + ks * 32 + lq * 8);
            acc3 = mfma16(a, b, acc3);
        }
#pragma unroll
        for (int j = 0; j < 4; ++j) {
            int row = wm * 16 + lq * 4 + j;
            int g = i * 64 + row;
            if (lr < 3 && g < n_e)
                out_act[(size_t)ridx[row] * 3 + lr] = acc3[j] + b3[e * 3 + lr];
        }
    }
}

// ---------- launch ----------
extern "C" void kernel_launch(void* const* d_in, const int* in_sizes, int n_in,
                              void* d_out, int out_size, void* d_ws, size_t ws_size,
                              hipStream_t stream) {
    (void)in_sizes; (void)n_in; (void)out_size;
    if (ws_size < WS_NEED) return;

    const float* p_i    = (const float*)d_in[0];
    const float* speed  = (const float*)d_in[1];
    const int*   command= (const int*)d_in[2];
    const float* sp_W1  = (const float*)d_in[3];
    const float* sp_b1  = (const float*)d_in[4];
    const float* sp_W2  = (const float*)d_in[5];
    const float* sp_b2  = (const float*)d_in[6];
    const float* sp_W3  = (const float*)d_in[7];
    const float* sp_b3  = (const float*)d_in[8];
    const float* vp_W1  = (const float*)d_in[9];
    const float* vp_b1  = (const float*)d_in[10];
    const float* vp_W2  = (const float*)d_in[11];
    const float* vp_b2  = (const float*)d_in[12];
    const float* vp_W3  = (const float*)d_in[13];
    const float* vp_b3  = (const float*)d_in[14];
    const float* join_W = (const float*)d_in[15];
    const float* join_b = (const float*)d_in[16];
    const float* ctrl_W1= (const float*)d_in[17];
    const float* ctrl_b1= (const float*)d_in[18];
    const float* ctrl_W2= (const float*)d_in[19];
    const float* ctrl_b2= (const float*)d_in[20];
    const float* ctrl_W3= (const float*)d_in[21];
    const float* ctrl_b3= (const float*)d_in[22];

    char* ws = (char*)d_ws;
    unsigned short* Aaug   = (unsigned short*)(ws + A_AUG_B);
    unsigned short* joined = (unsigned short*)(ws + JOINED_B);
    unsigned short* g1     = (unsigned short*)(ws + G1_B);
    unsigned short* wct    = (unsigned short*)(ws + WCT_B);
    unsigned short* spw2t  = (unsigned short*)(ws + SPW2T_B);
    unsigned short* spw3t  = (unsigned short*)(ws + SPW3T_B);
    unsigned short* vpw2t  = (unsigned short*)(ws + VPW2T_B);
    unsigned short* vpw3t  = (unsigned short*)(ws + VPW3T_B);
    unsigned short* c1t    = (unsigned short*)(ws + C1T_B);
    unsigned short* c2t    = (unsigned short*)(ws + C2T_B);
    unsigned short* c3t    = (unsigned short*)(ws + C3T_B);
    int* cnt    = (int*)(ws + CNT_B);
    int* sorted = (int*)(ws + SORTED_B);

    float* out_vp  = (float*)d_out;          // output dtype is FLOAT32 (reference returns f32)
    float* out_act = out_vp + NROWS;

    k_prep<<<1234, 256, 0, stream>>>(join_W, vp_W1, sp_W2, sp_W3, vp_W2, vp_W3,
                                     ctrl_W1, ctrl_W2, ctrl_W3,
                                     wct, spw2t, spw3t, vpw2t, vpw3t, c1t, c2t, c3t, cnt);
    k_sp_convert<<<256, 256, 0, stream>>>(p_i, speed, sp_W1, sp_b1, sp_b2, sp_b3,
                                          spw2t, spw3t, Aaug);
    k_scatter<<<128, 256, 0, stream>>>(command, cnt, sorted);
    k_join<<<1280, 256, 0, stream>>>(Aaug, wct, join_b, vp_b1, joined, g1);
    k_vp<<<256, 256, 0, stream>>>(g1, vpw2t, vpw3t, vp_b2, vp_b3, out_vp);
    k_ctrl<<<2048, 512, 0, stream>>>(joined, c1t, c2t, c3t, ctrl_b1, ctrl_b2, ctrl_b3,
                                     cnt, sorted, out_act);
}

// Round 6
// 317.787 us; speedup vs baseline: 1.3139x; 1.3139x over previous
//
#include <hip/hip_runtime.h>
#include <stdint.h>

#define NROWS 32768

typedef float f32x4 __attribute__((ext_vector_type(4)));
typedef __bf16 bfx8 __attribute__((ext_vector_type(8)));
typedef unsigned uint4v __attribute__((ext_vector_type(4)));

// ---------- helpers ----------
static __device__ __forceinline__ unsigned short f2bf(float f) {
    unsigned u = __builtin_bit_cast(unsigned, f);
    u += 0x7fffu + ((u >> 16) & 1u);   // RNE
    return (unsigned short)(u >> 16);
}

static __device__ __forceinline__ f32x4 mfma16(bfx8 a, bfx8 b, f32x4 c) {
    return __builtin_amdgcn_mfma_f32_16x16x32_bf16(a, b, c, 0, 0, 0);
}

// XOR swizzle of column index (elements, bf16): permutes 16B slots within 8-slot groups
static __device__ __forceinline__ int swz(int row, int col) {
    return col ^ ((row & 7) << 3);
}

// ---------- workspace layout (bytes) ----------
static constexpr size_t A_AUG_B  = 0;            // [32768][640] bf16 = 41,943,040
static constexpr size_t JOINED_B = 41943040;     // [32768][512] bf16 = 33,554,432
static constexpr size_t G1_B     = 75497472;     // [32768][128] bf16 =  8,388,608
static constexpr size_t WCT_B    = 83886080;     // [640][640] bf16   =    819,200
static constexpr size_t SPW2T_B  = 84705280;     // [128][128] bf16   =     32,768
static constexpr size_t SPW3T_B  = 84738048;     //                         32,768
static constexpr size_t VPW2T_B  = 84770816;     //                         32,768
static constexpr size_t VPW3T_B  = 84803584;     // [16][128] bf16    =      4,096
static constexpr size_t C1T_B    = 84807680;     // [4][256][512] bf16=  1,048,576
static constexpr size_t C2T_B    = 85856256;     // [4][256][256] bf16=    524,288
static constexpr size_t C3T_B    = 86380544;     // [4][16][256] bf16 =     32,768
static constexpr size_t CNT_B    = 86413312;     // 16 ints           =         64
static constexpr size_t SORTED_B = 86413376;     // [4][32768] int    =    524,288
static constexpr size_t WS_NEED  = 86937664;

// ---------- K0: weight transpose/convert + counter zero ----------
__global__ __launch_bounds__(256) void k_prep(
    const float* joinW, const float* vpW1, const float* spW2, const float* spW3,
    const float* vpW2, const float* vpW3, const float* c1, const float* c2, const float* c3,
    unsigned short* wct, unsigned short* spw2t, unsigned short* spw3t,
    unsigned short* vpw2t, unsigned short* vpw3t,
    unsigned short* c1t, unsigned short* c2t, unsigned short* c3t, int* cnt)
{
    int bid = blockIdx.x, tid = threadIdx.x;
    if (bid == 0 && tid < 16) cnt[tid] = 0;
    int region, idx0;
    if      (bid < 400)  { region = 0; idx0 = bid * 1024; }
    else if (bid < 416)  { region = 1; idx0 = (bid - 400) * 1024; }
    else if (bid < 432)  { region = 2; idx0 = (bid - 416) * 1024; }
    else if (bid < 448)  { region = 3; idx0 = (bid - 432) * 1024; }
    else if (bid < 450)  { region = 4; idx0 = (bid - 448) * 1024; }
    else if (bid < 962)  { region = 5; idx0 = (bid - 450) * 1024; }
    else if (bid < 1218) { region = 6; idx0 = (bid - 962) * 1024; }
    else                 { region = 7; idx0 = (bid - 1218) * 1024; }
    for (int j = 0; j < 4; ++j) {
        int idx = idx0 + tid + j * 256;
        switch (region) {
        case 0: { // WcT [640 n][640 k]: n<512 join_W[k][n]; n>=512 vp_W1[k][n-512] (k<512) else 0
            int n = idx / 640, k = idx % 640;
            float v = (n < 512) ? joinW[(size_t)k * 512 + n]
                                : (k < 512 ? vpW1[(size_t)k * 128 + (n - 512)] : 0.f);
            wct[idx] = f2bf(v);
        } break;
        case 1: { int n = idx >> 7, k = idx & 127; spw2t[idx] = f2bf(spW2[k * 128 + n]); } break;
        case 2: { int n = idx >> 7, k = idx & 127; spw3t[idx] = f2bf(spW3[k * 128 + n]); } break;
        case 3: { int n = idx >> 7, k = idx & 127; vpw2t[idx] = f2bf(vpW2[k * 128 + n]); } break;
        case 4: { int n = idx >> 7, k = idx & 127; vpw3t[idx] = f2bf(n == 0 ? vpW3[k] : 0.f); } break;
        case 5: { int e = idx >> 17, rem = idx & 131071, n = rem >> 9, k = rem & 511;
                  c1t[idx] = f2bf(c1[(size_t)e * 131072 + k * 256 + n]); } break;
        case 6: { int e = idx >> 16, rem = idx & 65535, n = rem >> 8, k = rem & 255;
                  c2t[idx] = f2bf(c2[(size_t)e * 65536 + k * 256 + n]); } break;
        case 7: { int e = idx >> 12, rem = idx & 4095, n = rem >> 8, k = rem & 255;
                  c3t[idx] = f2bf(n < 3 ? c3[(size_t)e * 768 + k * 3 + n] : 0.f); } break;
        }
    }
}

// ---------- K1: p_i f32->bf16 into A_aug[:,0:512] + sp-MLP -> A_aug[:,512:640] ----------
__global__ __launch_bounds__(256) void k_sp_convert(
    const float* p_i, const float* speed, const float* spW1, const float* spb1,
    const float* spb2, const float* spb3,
    const unsigned short* spw2t, const unsigned short* spw3t, unsigned short* Aaug)
{
    __shared__ alignas(16) unsigned short h1[128 * 128];  // swizzled
    __shared__ alignas(16) unsigned short h2[128 * 128];  // swizzled
    int bid = blockIdx.x, tid = threadIdx.x;
    int r0 = bid * 128;
    // p_i conversion: 128 rows x 512 cols, float4 -> ushort4
#pragma unroll 4
    for (int j = 0; j < 64; ++j) {
        int c = tid + j * 256;                 // 16384 float4 chunks
        int row = c >> 7, col4 = (c & 127) * 4;
        f32x4 v = *(const f32x4*)(p_i + (size_t)(r0 + row) * 512 + col4);
        ushort4 o;
        o.x = f2bf(v.x); o.y = f2bf(v.y); o.z = f2bf(v.z); o.w = f2bf(v.w);
        *(ushort4*)(Aaug + (size_t)(r0 + row) * 640 + col4) = o;
    }
    // h1 = relu(speed*W1 + b1) -> LDS (swizzled)
    for (int j = 0; j < 64; ++j) {
        int idx = tid + j * 256;
        int row = idx >> 7, col = idx & 127;
        float h = speed[r0 + row] * spW1[col] + spb1[col];
        h = h > 0.f ? h : 0.f;
        h1[row * 128 + swz(row, col)] = f2bf(h);
    }
    __syncthreads();

    int wave = tid >> 6, lane = tid & 63, lq = lane >> 4, lr = lane & 15;
    int wr = wave >> 1, wc = wave & 1;
    // GEMM1: h2 = relu(h1 @ spW2T + b2)
    f32x4 acc[4][4] = {};
#pragma unroll
    for (int ks = 0; ks < 4; ++ks) {
        bfx8 a[4], b[4];
#pragma unroll
        for (int mt = 0; mt < 4; ++mt) {
            int row = wr * 64 + mt * 16 + lr;
            a[mt] = *(const bfx8*)&h1[row * 128 + swz(row, ks * 32 + lq * 8)];
        }
#pragma unroll
        for (int nt = 0; nt < 4; ++nt) {
            int n = wc * 64 + nt * 16 + lr;
            b[nt] = *(const bfx8*)(spw2t + n * 128 + ks * 32 + lq * 8);
        }
#pragma unroll
        for (int mt = 0; mt < 4; ++mt)
#pragma unroll
            for (int nt = 0; nt < 4; ++nt)
                acc[mt][nt] = mfma16(a[mt], b[nt], acc[mt][nt]);
    }
#pragma unroll
    for (int mt = 0; mt < 4; ++mt)
#pragma unroll
        for (int nt = 0; nt < 4; ++nt)
#pragma unroll
            for (int j = 0; j < 4; ++j) {
                int row = wr * 64 + mt * 16 + lq * 4 + j;
                int col = wc * 64 + nt * 16 + lr;
                float v = acc[mt][nt][j] + spb2[col];
                v = v > 0.f ? v : 0.f;
                h2[row * 128 + swz(row, col)] = f2bf(v);
            }
    __syncthreads();
    // GEMM2: v = h2 @ spW3T + b3 (no relu) -> A_aug cols 512..639
    f32x4 acc2[4][4] = {};
#pragma unroll
    for (int ks = 0; ks < 4; ++ks) {
        bfx8 a[4], b[4];
#pragma unroll
        for (int mt = 0; mt < 4; ++mt) {
            int row = wr * 64 + mt * 16 + lr;
            a[mt] = *(const bfx8*)&h2[row * 128 + swz(row, ks * 32 + lq * 8)];
        }
#pragma unroll
        for (int nt = 0; nt < 4; ++nt) {
            int n = wc * 64 + nt * 16 + lr;
            b[nt] = *(const bfx8*)(spw3t + n * 128 + ks * 32 + lq * 8);
        }
#pragma unroll
        for (int mt = 0; mt < 4; ++mt)
#pragma unroll
            for (int nt = 0; nt < 4; ++nt)
                acc2[mt][nt] = mfma16(a[mt], b[nt], acc2[mt][nt]);
    }
#pragma unroll
    for (int mt = 0; mt < 4; ++mt)
#pragma unroll
        for (int nt = 0; nt < 4; ++nt)
#pragma unroll
            for (int j = 0; j < 4; ++j) {
                int row = wr * 64 + mt * 16 + lq * 4 + j;
                int col = wc * 64 + nt * 16 + lr;
                Aaug[(size_t)(r0 + row) * 640 + 512 + col] = f2bf(acc2[mt][nt][j] + spb3[col]);
            }
}

// ---------- K_route: bucket rows by command ----------
__global__ __launch_bounds__(256) void k_scatter(const int* command, int* cnt, int* sorted)
{
    __shared__ int lcnt[4], lbase[4];
    int tid = threadIdx.x;
    int r = blockIdx.x * 256 + tid;
    if (tid < 4) lcnt[tid] = 0;
    __syncthreads();
    int c = command[r] & 3;
    int lpos = atomicAdd(&lcnt[c], 1);
    __syncthreads();
    if (tid < 4) lbase[tid] = atomicAdd(&cnt[tid], lcnt[tid]);
    __syncthreads();
    sorted[c * NROWS + lbase[c] + lpos] = r;
}

// ---------- K2: joined+g1 = A_aug @ [join_W | vp_W1_pad]  (128x128 tile MFMA) ----------
__global__ __launch_bounds__(256) void k_join(
    const unsigned short* Aaug, const unsigned short* wct,
    const float* joinb, const float* vpb1, unsigned short* joined, unsigned short* g1)
{
    __shared__ alignas(16) unsigned short At[128 * 64];
    __shared__ alignas(16) unsigned short Bt[128 * 64];
    int d = blockIdx.x;
    int L = (d & 7) * 160 + (d >> 3);       // XCD swizzle (1280 % 8 == 0, bijective)
    int m0 = (L / 5) * 128, n0 = (L % 5) * 128;
    int tid = threadIdx.x, wave = tid >> 6, lane = tid & 63, lq = lane >> 4, lr = lane & 15;
    int wr = wave >> 1, wc = wave & 1;
    f32x4 acc[4][4] = {};
#pragma unroll 1
    for (int kt = 0; kt < 10; ++kt) {
#pragma unroll
        for (int c2 = 0; c2 < 4; ++c2) {
            int chunk = c2 * 256 + tid;       // 1024 chunks of 16B, 8 per 128B row
            int row = chunk >> 3, slot = chunk & 7;
            uint4v va = *(const uint4v*)(Aaug + (size_t)(m0 + row) * 640 + kt * 64 + slot * 8);
            uint4v vb = *(const uint4v*)(wct + (size_t)(n0 + row) * 640 + kt * 64 + slot * 8);
            *(uint4v*)&At[chunk * 8] = va;
            *(uint4v*)&Bt[chunk * 8] = vb;
        }
        __syncthreads();
#pragma unroll
        for (int ks = 0; ks < 2; ++ks) {
            bfx8 a[4], b[4];
#pragma unroll
            for (int mt = 0; mt < 4; ++mt)
                a[mt] = *(const bfx8*)&At[(wr * 64 + mt * 16 + lr) * 64 + ks * 32 + lq * 8];
#pragma unroll
            for (int nt = 0; nt < 4; ++nt)
                b[nt] = *(const bfx8*)&Bt[(wc * 64 + nt * 16 + lr) * 64 + ks * 32 + lq * 8];
#pragma unroll
            for (int mt = 0; mt < 4; ++mt)
#pragma unroll
                for (int nt = 0; nt < 4; ++nt)
                    acc[mt][nt] = mfma16(a[mt], b[nt], acc[mt][nt]);
        }
        __syncthreads();
    }
#pragma unroll
    for (int mt = 0; mt < 4; ++mt)
#pragma unroll
        for (int nt = 0; nt < 4; ++nt)
#pragma unroll
            for (int j = 0; j < 4; ++j) {
                int row = m0 + wr * 64 + mt * 16 + lq * 4 + j;
                int col = n0 + wc * 64 + nt * 16 + lr;
                float v = acc[mt][nt][j];
                if (col < 512) {
                    joined[(size_t)row * 512 + col] = f2bf(v + joinb[col]);
                } else {
                    v += vpb1[col - 512];
                    v = v > 0.f ? v : 0.f;
                    g1[(size_t)row * 128 + (col - 512)] = f2bf(v);
                }
            }
}

// ---------- K3: vp tail: g2 = relu(g1@W2+b2); v_p = g2@W3+b3 -> out[0:B] (f32 out) ----------
__global__ __launch_bounds__(256) void k_vp(
    const unsigned short* g1, const unsigned short* vpw2t, const unsigned short* vpw3t,
    const float* vpb2, const float* vpb3, float* out_vp)
{
    __shared__ alignas(16) unsigned short gt[128 * 128];   // swizzled
    __shared__ alignas(16) unsigned short h2[128 * 128];   // swizzled
    int bid = blockIdx.x, tid = threadIdx.x;
    int r0 = bid * 128;
    // stage g1 tile: read linear global, write swizzled LDS (reg-staged)
#pragma unroll
    for (int c2 = 0; c2 < 8; ++c2) {
        int chunk = c2 * 256 + tid;            // 2048 chunks of 16B, 16 per 256B row
        int row = chunk >> 4, slot = chunk & 15;
        int sslot = slot ^ (row & 7);
        uint4v v = *(const uint4v*)(g1 + (size_t)(r0 + row) * 128 + slot * 8);
        *(uint4v*)&gt[row * 128 + sslot * 8] = v;
    }
    __syncthreads();
    int wave = tid >> 6, lane = tid & 63, lq = lane >> 4, lr = lane & 15;
    int wr = wave >> 1, wc = wave & 1;
    // GEMM1: h2 = relu(gt @ vpW2T + b2)
    f32x4 acc[4][4] = {};
#pragma unroll
    for (int ks = 0; ks < 4; ++ks) {
        bfx8 a[4], b[4];
#pragma unroll
        for (int mt = 0; mt < 4; ++mt) {
            int row = wr * 64 + mt * 16 + lr;
            a[mt] = *(const bfx8*)&gt[row * 128 + swz(row, ks * 32 + lq * 8)];
        }
#pragma unroll
        for (int nt = 0; nt < 4; ++nt) {
            int n = wc * 64 + nt * 16 + lr;
            b[nt] = *(const bfx8*)(vpw2t + n * 128 + ks * 32 + lq * 8);
        }
#pragma unroll
        for (int mt = 0; mt < 4; ++mt)
#pragma unroll
            for (int nt = 0; nt < 4; ++nt)
                acc[mt][nt] = mfma16(a[mt], b[nt], acc[mt][nt]);
    }
#pragma unroll
    for (int mt = 0; mt < 4; ++mt)
#pragma unroll
        for (int nt = 0; nt < 4; ++nt)
#pragma unroll
            for (int j = 0; j < 4; ++j) {
                int row = wr * 64 + mt * 16 + lq * 4 + j;
                int col = wc * 64 + nt * 16 + lr;
                float v = acc[mt][nt][j] + vpb2[col];
                v = v > 0.f ? v : 0.f;
                h2[row * 128 + swz(row, col)] = f2bf(v);
            }
    __syncthreads();
    // GEMM2: v_p = h2 @ vpW3T(pad N=16) + b3; only col 0 valid
    f32x4 acc2[2] = {};
#pragma unroll
    for (int ks = 0; ks < 4; ++ks) {
        bfx8 b = *(const bfx8*)(vpw3t + lr * 128 + ks * 32 + lq * 8);
#pragma unroll
        for (int mt = 0; mt < 2; ++mt) {
            int row = wave * 32 + mt * 16 + lr;
            bfx8 a = *(const bfx8*)&h2[row * 128 + swz(row, ks * 32 + lq * 8)];
            acc2[mt] = mfma16(a, b, acc2[mt]);
        }
    }
    if (lr == 0) {
#pragma unroll
        for (int mt = 0; mt < 2; ++mt)
#pragma unroll
            for (int j = 0; j < 4; ++j) {
                int row = wave * 32 + mt * 16 + lq * 4 + j;
                out_vp[r0 + row] = acc2[mt][j] + vpb3[0];
            }
    }
}

// ---------- K4: routed control heads, LDS-staged GEMM (M=128/block, N=256, f32 out) ----------
// 8 waves: GEMM1/2 wave layout 2M x 4N (wave M=64, N=64). LDS: h 64KB + Bst 32KB + Ast 16KB.
__global__ __launch_bounds__(512) void k_ctrl(
    const unsigned short* joined, const unsigned short* c1t, const unsigned short* c2t,
    const unsigned short* c3t, const float* b1, const float* b2, const float* b3,
    const int* cnt, const int* sorted, float* out_act)
{
    __shared__ alignas(16) unsigned short hls[128 * 256];  // h, then h2 (swizzled)
    __shared__ alignas(16) unsigned short Ast[128 * 64];   // A K-chunk (swizzled)
    __shared__ alignas(16) unsigned short Bst[256 * 64];   // W K-chunk (swizzled)
    __shared__ int ridx[128];
    int bid = blockIdx.x;
    int e = bid >> 8, i = bid & 255;
    int n_e = cnt[e];
    if (i * 128 >= n_e) return;
    int tid = threadIdx.x;
    if (tid < 128) {
        int g = i * 128 + tid;
        ridx[tid] = sorted[e * NROWS + (g < n_e ? g : n_e - 1)];
    }
    __syncthreads();
    int wave = tid >> 6, lane = tid & 63, lq = lane >> 4, lr = lane & 15;
    int wm = wave & 1, wn = wave >> 1;        // 2 M-waves x 4 N-waves
    const unsigned short* W1 = c1t + e * (256 * 512);
    const unsigned short* W2 = c2t + e * (256 * 256);
    const unsigned short* W3 = c3t + e * (16 * 256);

    // ---- GEMM1: h = relu(A @ W1T + b1), K=512 in 8 chunks of 64 ----
    f32x4 acc[4][4] = {};
#pragma unroll 1
    for (int kt = 0; kt < 8; ++kt) {
        // stage A chunk [128 rows][64 k] (gathered rows)
#pragma unroll
        for (int it = 0; it < 2; ++it) {
            int idx = it * 512 + tid;          // 1024 chunks of 16B
            int row = idx >> 3, slot = idx & 7;
            uint4v v = *(const uint4v*)(joined + (size_t)ridx[row] * 512 + kt * 64 + slot * 8);
            *(uint4v*)&Ast[row * 64 + (slot ^ (row & 7)) * 8] = v;
        }
        // stage B chunk [256 n][64 k]
#pragma unroll
        for (int it = 0; it < 4; ++it) {
            int idx = it * 512 + tid;          // 2048 chunks of 16B
            int n = idx >> 3, slot = idx & 7;
            uint4v v = *(const uint4v*)(W1 + (size_t)n * 512 + kt * 64 + slot * 8);
            *(uint4v*)&Bst[n * 64 + (slot ^ (n & 7)) * 8] = v;
        }
        __syncthreads();
#pragma unroll
        for (int ks = 0; ks < 2; ++ks) {
            bfx8 a[4], b[4];
#pragma unroll
            for (int mt = 0; mt < 4; ++mt) {
                int row = wm * 64 + mt * 16 + lr;
                a[mt] = *(const bfx8*)&Ast[row * 64 + ((ks * 32 + lq * 8) ^ ((row & 7) << 3))];
            }
#pragma unroll
            for (int nt = 0; nt < 4; ++nt) {
                int n = wn * 64 + nt * 16 + lr;
                b[nt] = *(const bfx8*)&Bst[n * 64 + ((ks * 32 + lq * 8) ^ ((n & 7) << 3))];
            }
#pragma unroll
            for (int mt = 0; mt < 4; ++mt)
#pragma unroll
                for (int nt = 0; nt < 4; ++nt)
                    acc[mt][nt] = mfma16(a[mt], b[nt], acc[mt][nt]);
        }
        __syncthreads();
    }
    // write h to LDS (bias+relu)
#pragma unroll
    for (int mt = 0; mt < 4; ++mt)
#pragma unroll
        for (int nt = 0; nt < 4; ++nt)
#pragma unroll
            for (int j = 0; j < 4; ++j) {
                int row = wm * 64 + mt * 16 + lq * 4 + j;
                int col = wn * 64 + nt * 16 + lr;
                float v = acc[mt][nt][j] + b1[e * 256 + col];
                v = v > 0.f ? v : 0.f;
                hls[row * 256 + swz(row, col)] = f2bf(v);
            }
    __syncthreads();

    // ---- GEMM2: h2 = relu(h @ W2T + b2), K=256 in 4 chunks of 64 ----
    f32x4 acc2[4][4] = {};
#pragma unroll 1
    for (int kt = 0; kt < 4; ++kt) {
#pragma unroll
        for (int it = 0; it < 4; ++it) {
            int idx = it * 512 + tid;
            int n = idx >> 3, slot = idx & 7;
            uint4v v = *(const uint4v*)(W2 + (size_t)n * 256 + kt * 64 + slot * 8);
            *(uint4v*)&Bst[n * 64 + (slot ^ (n & 7)) * 8] = v;
        }
        __syncthreads();
#pragma unroll
        for (int ks = 0; ks < 2; ++ks) {
            bfx8 a[4], b[4];
#pragma unroll
            for (int mt = 0; mt < 4; ++mt) {
                int row = wm * 64 + mt * 16 + lr;
                a[mt] = *(const bfx8*)&hls[row * 256 + swz(row, kt * 64 + ks * 32 + lq * 8)];
            }
#pragma unroll
            for (int nt = 0; nt < 4; ++nt) {
                int n = wn * 64 + nt * 16 + lr;
                b[nt] = *(const bfx8*)&Bst[n * 64 + ((ks * 32 + lq * 8) ^ ((n & 7) << 3))];
            }
#pragma unroll
            for (int mt = 0; mt < 4; ++mt)
#pragma unroll
                for (int nt = 0; nt < 4; ++nt)
                    acc2[mt][nt] = mfma16(a[mt], b[nt], acc2[mt][nt]);
        }
        __syncthreads();
    }
    // write h2 back into hls (bias+relu); all reads of h are done (last barrier above)
#pragma unroll
    for (int mt = 0; mt < 4; ++mt)
#pragma unroll
        for (int nt = 0; nt < 4; ++nt)
#pragma unroll
            for (int j = 0; j < 4; ++j) {
                int row = wm * 64 + mt * 16 + lq * 4 + j;
                int col = wn * 64 + nt * 16 + lr;
                float v = acc2[mt][nt][j] + b2[e * 256 + col];
                v = v > 0.f ? v : 0.f;
                hls[row * 256 + swz(row, col)] = f2bf(v);
            }
    __syncthreads();

    // ---- GEMM3: a = h2 @ W3T(pad N=16) + b3; each wave owns 16 rows; cols 0..2 valid ----
    {
        f32x4 acc3 = {};
#pragma unroll
        for (int ks = 0; ks < 8; ++ks) {
            int row = wave * 16 + lr;
            bfx8 a = *(const bfx8*)&hls[row * 256 + swz(row, ks * 32 + lq * 8)];
            bfx8 b = *(const bfx8*)(W3 + lr * 256 + ks * 32 + lq * 8);
            acc3 = mfma16(a, b, acc3);
        }
#pragma unroll
        for (int j = 0; j < 4; ++j) {
            int row = wave * 16 + lq * 4 + j;
            int g = i * 128 + row;
            if (lr < 3 && g < n_e)
                out_act[(size_t)ridx[row] * 3 + lr] = acc3[j] + b3[e * 3 + lr];
        }
    }
}

// ---------- launch ----------
extern "C" void kernel_launch(void* const* d_in, const int* in_sizes, int n_in,
                              void* d_out, int out_size, void* d_ws, size_t ws_size,
                              hipStream_t stream) {
    (void)in_sizes; (void)n_in; (void)out_size;
    if (ws_size < WS_NEED) return;

    const float* p_i    = (const float*)d_in[0];
    const float* speed  = (const float*)d_in[1];
    const int*   command= (const int*)d_in[2];
    const float* sp_W1  = (const float*)d_in[3];
    const float* sp_b1  = (const float*)d_in[4];
    const float* sp_W2  = (const float*)d_in[5];
    const float* sp_b2  = (const float*)d_in[6];
    const float* sp_W3  = (const float*)d_in[7];
    const float* sp_b3  = (const float*)d_in[8];
    const float* vp_W1  = (const float*)d_in[9];
    const float* vp_b1  = (const float*)d_in[10];
    const float* vp_W2  = (const float*)d_in[11];
    const float* vp_b2  = (const float*)d_in[12];
    const float* vp_W3  = (const float*)d_in[13];
    const float* vp_b3  = (const float*)d_in[14];
    const float* join_W = (const float*)d_in[15];
    const float* join_b = (const float*)d_in[16];
    const float* ctrl_W1= (const float*)d_in[17];
    const float* ctrl_b1= (const float*)d_in[18];
    const float* ctrl_W2= (const float*)d_in[19];
    const float* ctrl_b2= (const float*)d_in[20];
    const float* ctrl_W3= (const float*)d_in[21];
    const float* ctrl_b3= (const float*)d_in[22];

    char* ws = (char*)d_ws;
    unsigned short* Aaug   = (unsigned short*)(ws + A_AUG_B);
    unsigned short* joined = (unsigned short*)(ws + JOINED_B);
    unsigned short* g1     = (unsigned short*)(ws + G1_B);
    unsigned short* wct    = (unsigned short*)(ws + WCT_B);
    unsigned short* spw2t  = (unsigned short*)(ws + SPW2T_B);
    unsigned short* spw3t  = (unsigned short*)(ws + SPW3T_B);
    unsigned short* vpw2t  = (unsigned short*)(ws + VPW2T_B);
    unsigned short* vpw3t  = (unsigned short*)(ws + VPW3T_B);
    unsigned short* c1t    = (unsigned short*)(ws + C1T_B);
    unsigned short* c2t    = (unsigned short*)(ws + C2T_B);
    unsigned short* c3t    = (unsigned short*)(ws + C3T_B);
    int* cnt    = (int*)(ws + CNT_B);
    int* sorted = (int*)(ws + SORTED_B);

    float* out_vp  = (float*)d_out;          // output dtype is FLOAT32
    float* out_act = out_vp + NROWS;

    k_prep<<<1234, 256, 0, stream>>>(join_W, vp_W1, sp_W2, sp_W3, vp_W2, vp_W3,
                                     ctrl_W1, ctrl_W2, ctrl_W3,
                                     wct, spw2t, spw3t, vpw2t, vpw3t, c1t, c2t, c3t, cnt);
    k_sp_convert<<<256, 256, 0, stream>>>(p_i, speed, sp_W1, sp_b1, sp_b2, sp_b3,
                                          spw2t, spw3t, Aaug);
    k_scatter<<<128, 256, 0, stream>>>(command, cnt, sorted);
    k_join<<<1280, 256, 0, stream>>>(Aaug, wct, join_b, vp_b1, joined, g1);
    k_vp<<<256, 256, 0, stream>>>(g1, vpw2t, vpw3t, vp_b2, vp_b3, out_vp);
    k_ctrl<<<1024, 512, 0, stream>>>(joined, c1t, c2t, c3t, ctrl_b1, ctrl_b2, ctrl_b3,
                                     cnt, sorted, out_act);
}

// Round 7
// 304.544 us; speedup vs baseline: 1.3710x; 1.0435x over previous
//
#include <hip/hip_runtime.h>
#include <stdint.h>

#define NROWS 32768

typedef float f32x4 __attribute__((ext_vector_type(4)));
typedef __bf16 bfx8 __attribute__((ext_vector_type(8)));
typedef unsigned uint4v __attribute__((ext_vector_type(4)));

// ---------- helpers ----------
static __device__ __forceinline__ unsigned short f2bf(float f) {
    unsigned u = __builtin_bit_cast(unsigned, f);
    u += 0x7fffu + ((u >> 16) & 1u);   // RNE
    return (unsigned short)(u >> 16);
}

static __device__ __forceinline__ f32x4 mfma16(bfx8 a, bfx8 b, f32x4 c) {
    return __builtin_amdgcn_mfma_f32_16x16x32_bf16(a, b, c, 0, 0, 0);
}

// XOR swizzle of column index (elements, bf16): permutes 16B slots within 8-slot groups
static __device__ __forceinline__ int swz(int row, int col) {
    return col ^ ((row & 7) << 3);
}

// ---------- workspace layout (bytes) ----------
static constexpr size_t A_AUG_B  = 0;            // [32768][640] bf16 = 41,943,040
static constexpr size_t JOINED_B = 41943040;     // [32768][512] bf16 = 33,554,432
static constexpr size_t G1_B     = 75497472;     // [32768][128] bf16 =  8,388,608
static constexpr size_t WCT_B    = 83886080;     // [640][640] bf16   =    819,200
static constexpr size_t SPW2T_B  = 84705280;     // [128][128] bf16   =     32,768
static constexpr size_t SPW3T_B  = 84738048;     //                         32,768
static constexpr size_t VPW2T_B  = 84770816;     //                         32,768
static constexpr size_t VPW3T_B  = 84803584;     // [16][128] bf16    =      4,096
static constexpr size_t C1T_B    = 84807680;     // [4][256][512] bf16=  1,048,576
static constexpr size_t C2T_B    = 85856256;     // [4][256][256] bf16=    524,288
static constexpr size_t C3T_B    = 86380544;     // [4][16][256] bf16 =     32,768
static constexpr size_t CNT_B    = 86413312;     // 16 ints           =         64
static constexpr size_t SORTED_B = 86413376;     // [4][32768] int    =    524,288
static constexpr size_t WS_NEED  = 86937664;

// ---------- K0: weight transpose/convert + counter zero ----------
__global__ __launch_bounds__(256) void k_prep(
    const float* joinW, const float* vpW1, const float* spW2, const float* spW3,
    const float* vpW2, const float* vpW3, const float* c1, const float* c2, const float* c3,
    unsigned short* wct, unsigned short* spw2t, unsigned short* spw3t,
    unsigned short* vpw2t, unsigned short* vpw3t,
    unsigned short* c1t, unsigned short* c2t, unsigned short* c3t, int* cnt)
{
    int bid = blockIdx.x, tid = threadIdx.x;
    if (bid == 0 && tid < 16) cnt[tid] = 0;
    int region, idx0;
    if      (bid < 400)  { region = 0; idx0 = bid * 1024; }
    else if (bid < 416)  { region = 1; idx0 = (bid - 400) * 1024; }
    else if (bid < 432)  { region = 2; idx0 = (bid - 416) * 1024; }
    else if (bid < 448)  { region = 3; idx0 = (bid - 432) * 1024; }
    else if (bid < 450)  { region = 4; idx0 = (bid - 448) * 1024; }
    else if (bid < 962)  { region = 5; idx0 = (bid - 450) * 1024; }
    else if (bid < 1218) { region = 6; idx0 = (bid - 962) * 1024; }
    else                 { region = 7; idx0 = (bid - 1218) * 1024; }
    for (int j = 0; j < 4; ++j) {
        int idx = idx0 + tid + j * 256;
        switch (region) {
        case 0: { // WcT [640 n][640 k]: n<512 join_W[k][n]; n>=512 vp_W1[k][n-512] (k<512) else 0
            int n = idx / 640, k = idx % 640;
            float v = (n < 512) ? joinW[(size_t)k * 512 + n]
                                : (k < 512 ? vpW1[(size_t)k * 128 + (n - 512)] : 0.f);
            wct[idx] = f2bf(v);
        } break;
        case 1: { int n = idx >> 7, k = idx & 127; spw2t[idx] = f2bf(spW2[k * 128 + n]); } break;
        case 2: { int n = idx >> 7, k = idx & 127; spw3t[idx] = f2bf(spW3[k * 128 + n]); } break;
        case 3: { int n = idx >> 7, k = idx & 127; vpw2t[idx] = f2bf(vpW2[k * 128 + n]); } break;
        case 4: { int n = idx >> 7, k = idx & 127; vpw3t[idx] = f2bf(n == 0 ? vpW3[k] : 0.f); } break;
        case 5: { int e = idx >> 17, rem = idx & 131071, n = rem >> 9, k = rem & 511;
                  c1t[idx] = f2bf(c1[(size_t)e * 131072 + k * 256 + n]); } break;
        case 6: { int e = idx >> 16, rem = idx & 65535, n = rem >> 8, k = rem & 255;
                  c2t[idx] = f2bf(c2[(size_t)e * 65536 + k * 256 + n]); } break;
        case 7: { int e = idx >> 12, rem = idx & 4095, n = rem >> 8, k = rem & 255;
                  c3t[idx] = f2bf(n < 3 ? c3[(size_t)e * 768 + k * 3 + n] : 0.f); } break;
        }
    }
}

// ---------- K1: p_i f32->bf16 into A_aug[:,0:512] + sp-MLP -> A_aug[:,512:640] ----------
__global__ __launch_bounds__(256) void k_sp_convert(
    const float* p_i, const float* speed, const float* spW1, const float* spb1,
    const float* spb2, const float* spb3,
    const unsigned short* spw2t, const unsigned short* spw3t, unsigned short* Aaug)
{
    __shared__ alignas(16) unsigned short h1[128 * 128];  // swizzled
    __shared__ alignas(16) unsigned short h2[128 * 128];  // swizzled
    int bid = blockIdx.x, tid = threadIdx.x;
    int r0 = bid * 128;
    // p_i conversion: 128 rows x 512 cols, float4 -> ushort4
#pragma unroll 4
    for (int j = 0; j < 64; ++j) {
        int c = tid + j * 256;                 // 16384 float4 chunks
        int row = c >> 7, col4 = (c & 127) * 4;
        f32x4 v = *(const f32x4*)(p_i + (size_t)(r0 + row) * 512 + col4);
        ushort4 o;
        o.x = f2bf(v.x); o.y = f2bf(v.y); o.z = f2bf(v.z); o.w = f2bf(v.w);
        *(ushort4*)(Aaug + (size_t)(r0 + row) * 640 + col4) = o;
    }
    // h1 = relu(speed*W1 + b1) -> LDS (swizzled)
    for (int j = 0; j < 64; ++j) {
        int idx = tid + j * 256;
        int row = idx >> 7, col = idx & 127;
        float h = speed[r0 + row] * spW1[col] + spb1[col];
        h = h > 0.f ? h : 0.f;
        h1[row * 128 + swz(row, col)] = f2bf(h);
    }
    __syncthreads();

    int wave = tid >> 6, lane = tid & 63, lq = lane >> 4, lr = lane & 15;
    int wr = wave >> 1, wc = wave & 1;
    // GEMM1: h2 = relu(h1 @ spW2T + b2)
    f32x4 acc[4][4] = {};
#pragma unroll
    for (int ks = 0; ks < 4; ++ks) {
        bfx8 a[4], b[4];
#pragma unroll
        for (int mt = 0; mt < 4; ++mt) {
            int row = wr * 64 + mt * 16 + lr;
            a[mt] = *(const bfx8*)&h1[row * 128 + swz(row, ks * 32 + lq * 8)];
        }
#pragma unroll
        for (int nt = 0; nt < 4; ++nt) {
            int n = wc * 64 + nt * 16 + lr;
            b[nt] = *(const bfx8*)(spw2t + n * 128 + ks * 32 + lq * 8);
        }
#pragma unroll
        for (int mt = 0; mt < 4; ++mt)
#pragma unroll
            for (int nt = 0; nt < 4; ++nt)
                acc[mt][nt] = mfma16(a[mt], b[nt], acc[mt][nt]);
    }
#pragma unroll
    for (int mt = 0; mt < 4; ++mt)
#pragma unroll
        for (int nt = 0; nt < 4; ++nt)
#pragma unroll
            for (int j = 0; j < 4; ++j) {
                int row = wr * 64 + mt * 16 + lq * 4 + j;
                int col = wc * 64 + nt * 16 + lr;
                float v = acc[mt][nt][j] + spb2[col];
                v = v > 0.f ? v : 0.f;
                h2[row * 128 + swz(row, col)] = f2bf(v);
            }
    __syncthreads();
    // GEMM2: v = h2 @ spW3T + b3 (no relu) -> A_aug cols 512..639
    f32x4 acc2[4][4] = {};
#pragma unroll
    for (int ks = 0; ks < 4; ++ks) {
        bfx8 a[4], b[4];
#pragma unroll
        for (int mt = 0; mt < 4; ++mt) {
            int row = wr * 64 + mt * 16 + lr;
            a[mt] = *(const bfx8*)&h2[row * 128 + swz(row, ks * 32 + lq * 8)];
        }
#pragma unroll
        for (int nt = 0; nt < 4; ++nt) {
            int n = wc * 64 + nt * 16 + lr;
            b[nt] = *(const bfx8*)(spw3t + n * 128 + ks * 32 + lq * 8);
        }
#pragma unroll
        for (int mt = 0; mt < 4; ++mt)
#pragma unroll
            for (int nt = 0; nt < 4; ++nt)
                acc2[mt][nt] = mfma16(a[mt], b[nt], acc2[mt][nt]);
    }
#pragma unroll
    for (int mt = 0; mt < 4; ++mt)
#pragma unroll
        for (int nt = 0; nt < 4; ++nt)
#pragma unroll
            for (int j = 0; j < 4; ++j) {
                int row = wr * 64 + mt * 16 + lq * 4 + j;
                int col = wc * 64 + nt * 16 + lr;
                Aaug[(size_t)(r0 + row) * 640 + 512 + col] = f2bf(acc2[mt][nt][j] + spb3[col]);
            }
}

// ---------- K_route: bucket rows by command ----------
__global__ __launch_bounds__(256) void k_scatter(const int* command, int* cnt, int* sorted)
{
    __shared__ int lcnt[4], lbase[4];
    int tid = threadIdx.x;
    int r = blockIdx.x * 256 + tid;
    if (tid < 4) lcnt[tid] = 0;
    __syncthreads();
    int c = command[r] & 3;
    int lpos = atomicAdd(&lcnt[c], 1);
    __syncthreads();
    if (tid < 4) lbase[tid] = atomicAdd(&cnt[tid], lcnt[tid]);
    __syncthreads();
    sorted[c * NROWS + lbase[c] + lpos] = r;
}

// ---------- K2: joined+g1 = A_aug @ [join_W | vp_W1_pad]  (128x128 tile MFMA) ----------
// reg-staged, XOR-swizzled LDS (R6 had 9.8M bank conflicts: unswizzled stride-128B reads),
// T14 prefetch: next K-chunk loads issued before the MFMA phase.
__global__ __launch_bounds__(256) void k_join(
    const unsigned short* Aaug, const unsigned short* wct,
    const float* joinb, const float* vpb1, unsigned short* joined, unsigned short* g1)
{
    __shared__ alignas(16) unsigned short At[128 * 64];
    __shared__ alignas(16) unsigned short Bt[128 * 64];
    int d = blockIdx.x;
    int L = (d & 7) * 160 + (d >> 3);       // XCD swizzle (1280 % 8 == 0, bijective)
    int m0 = (L / 5) * 128, n0 = (L % 5) * 128;
    int tid = threadIdx.x, wave = tid >> 6, lane = tid & 63, lq = lane >> 4, lr = lane & 15;
    int wr = wave >> 1, wc = wave & 1;

    // staging geometry: thread handles rows r0t + {0,32,64,96}, fixed slot s0t.
    // swizzled slot ss = s0t ^ (r0t&7) is c2-invariant since rows step by 32 (≡0 mod 8).
    int r0t = tid >> 3, s0t = tid & 7;
    int ss = s0t ^ (r0t & 7);
    const unsigned short* aब = Aaug + (size_t)(m0 + r0t) * 640 + s0t * 8;
    const unsigned short* bब = wct + (size_t)(n0 + r0t) * 640 + s0t * 8;
    unsigned short* lA = &At[r0t * 64 + ss * 8];
    unsigned short* lB = &Bt[r0t * 64 + ss * 8];

    uint4v ra[4], rb[4];
#pragma unroll
    for (int c2 = 0; c2 < 4; ++c2) {        // prologue: chunk 0 loads
        ra[c2] = *(const uint4v*)(aब + c2 * (32 * 640));
        rb[c2] = *(const uint4v*)(bब + c2 * (32 * 640));
    }
    f32x4 acc[4][4] = {};
#pragma unroll 1
    for (int kt = 0; kt < 10; ++kt) {
#pragma unroll
        for (int c2 = 0; c2 < 4; ++c2) {    // ds_write staged regs (compiler waits vmcnt)
            *(uint4v*)(lA + c2 * (32 * 64)) = ra[c2];
            *(uint4v*)(lB + c2 * (32 * 64)) = rb[c2];
        }
        __syncthreads();
        if (kt < 9) {                        // issue next chunk; latency hides under MFMA
#pragma unroll
            for (int c2 = 0; c2 < 4; ++c2) {
                ra[c2] = *(const uint4v*)(aब + c2 * (32 * 640) + (kt + 1) * 64);
                rb[c2] = *(const uint4v*)(bब + c2 * (32 * 640) + (kt + 1) * 64);
            }
        }
#pragma unroll
        for (int ks = 0; ks < 2; ++ks) {
            bfx8 a[4], b[4];
#pragma unroll
            for (int mt = 0; mt < 4; ++mt) {
                int row = wr * 64 + mt * 16 + lr;
                a[mt] = *(const bfx8*)&At[row * 64 + ((ks * 32 + lq * 8) ^ ((row & 7) << 3))];
            }
#pragma unroll
            for (int nt = 0; nt < 4; ++nt) {
                int n = wc * 64 + nt * 16 + lr;
                b[nt] = *(const bfx8*)&Bt[n * 64 + ((ks * 32 + lq * 8) ^ ((n & 7) << 3))];
            }
#pragma unroll
            for (int mt = 0; mt < 4; ++mt)
#pragma unroll
                for (int nt = 0; nt < 4; ++nt)
                    acc[mt][nt] = mfma16(a[mt], b[nt], acc[mt][nt]);
        }
        __syncthreads();
    }
#pragma unroll
    for (int mt = 0; mt < 4; ++mt)
#pragma unroll
        for (int nt = 0; nt < 4; ++nt)
#pragma unroll
            for (int j = 0; j < 4; ++j) {
                int row = m0 + wr * 64 + mt * 16 + lq * 4 + j;
                int col = n0 + wc * 64 + nt * 16 + lr;
                float v = acc[mt][nt][j];
                if (col < 512) {
                    joined[(size_t)row * 512 + col] = f2bf(v + joinb[col]);
                } else {
                    v += vpb1[col - 512];
                    v = v > 0.f ? v : 0.f;
                    g1[(size_t)row * 128 + (col - 512)] = f2bf(v);
                }
            }
}

// ---------- K3: vp tail: g2 = relu(g1@W2+b2); v_p = g2@W3+b3 -> out[0:B] (f32 out) ----------
__global__ __launch_bounds__(256) void k_vp(
    const unsigned short* g1, const unsigned short* vpw2t, const unsigned short* vpw3t,
    const float* vpb2, const float* vpb3, float* out_vp)
{
    __shared__ alignas(16) unsigned short gt[128 * 128];   // swizzled
    __shared__ alignas(16) unsigned short h2[128 * 128];   // swizzled
    int bid = blockIdx.x, tid = threadIdx.x;
    int r0 = bid * 128;
    // stage g1 tile: read linear global, write swizzled LDS (reg-staged)
#pragma unroll
    for (int c2 = 0; c2 < 8; ++c2) {
        int chunk = c2 * 256 + tid;            // 2048 chunks of 16B, 16 per 256B row
        int row = chunk >> 4, slot = chunk & 15;
        int sslot = slot ^ (row & 7);
        uint4v v = *(const uint4v*)(g1 + (size_t)(r0 + row) * 128 + slot * 8);
        *(uint4v*)&gt[row * 128 + sslot * 8] = v;
    }
    __syncthreads();
    int wave = tid >> 6, lane = tid & 63, lq = lane >> 4, lr = lane & 15;
    int wr = wave >> 1, wc = wave & 1;
    // GEMM1: h2 = relu(gt @ vpW2T + b2)
    f32x4 acc[4][4] = {};
#pragma unroll
    for (int ks = 0; ks < 4; ++ks) {
        bfx8 a[4], b[4];
#pragma unroll
        for (int mt = 0; mt < 4; ++mt) {
            int row = wr * 64 + mt * 16 + lr;
            a[mt] = *(const bfx8*)&gt[row * 128 + swz(row, ks * 32 + lq * 8)];
        }
#pragma unroll
        for (int nt = 0; nt < 4; ++nt) {
            int n = wc * 64 + nt * 16 + lr;
            b[nt] = *(const bfx8*)(vpw2t + n * 128 + ks * 32 + lq * 8);
        }
#pragma unroll
        for (int mt = 0; mt < 4; ++mt)
#pragma unroll
            for (int nt = 0; nt < 4; ++nt)
                acc[mt][nt] = mfma16(a[mt], b[nt], acc[mt][nt]);
    }
#pragma unroll
    for (int mt = 0; mt < 4; ++mt)
#pragma unroll
        for (int nt = 0; nt < 4; ++nt)
#pragma unroll
            for (int j = 0; j < 4; ++j) {
                int row = wr * 64 + mt * 16 + lq * 4 + j;
                int col = wc * 64 + nt * 16 + lr;
                float v = acc[mt][nt][j] + vpb2[col];
                v = v > 0.f ? v : 0.f;
                h2[row * 128 + swz(row, col)] = f2bf(v);
            }
    __syncthreads();
    // GEMM2: v_p = h2 @ vpW3T(pad N=16) + b3; only col 0 valid
    f32x4 acc2[2] = {};
#pragma unroll
    for (int ks = 0; ks < 4; ++ks) {
        bfx8 b = *(const bfx8*)(vpw3t + lr * 128 + ks * 32 + lq * 8);
#pragma unroll
        for (int mt = 0; mt < 2; ++mt) {
            int row = wave * 32 + mt * 16 + lr;
            bfx8 a = *(const bfx8*)&h2[row * 128 + swz(row, ks * 32 + lq * 8)];
            acc2[mt] = mfma16(a, b, acc2[mt]);
        }
    }
    if (lr == 0) {
#pragma unroll
        for (int mt = 0; mt < 2; ++mt)
#pragma unroll
            for (int j = 0; j < 4; ++j) {
                int row = wave * 32 + mt * 16 + lq * 4 + j;
                out_vp[r0 + row] = acc2[mt][j] + vpb3[0];
            }
    }
}

// ---------- K4: routed control heads, LDS-staged GEMM (M=128/block, N=256, f32 out) ----------
__global__ __launch_bounds__(512) void k_ctrl(
    const unsigned short* joined, const unsigned short* c1t, const unsigned short* c2t,
    const unsigned short* c3t, const float* b1, const float* b2, const float* b3,
    const int* cnt, const int* sorted, float* out_act)
{
    __shared__ alignas(16) unsigned short hls[128 * 256];  // h, then h2 (swizzled)
    __shared__ alignas(16) unsigned short Ast[128 * 64];   // A K-chunk (swizzled)
    __shared__ alignas(16) unsigned short Bst[256 * 64];   // W K-chunk (swizzled)
    __shared__ int ridx[128];
    int bid = blockIdx.x;
    int e = bid >> 8, i = bid & 255;
    int n_e = cnt[e];
    if (i * 128 >= n_e) return;
    int tid = threadIdx.x;
    if (tid < 128) {
        int g = i * 128 + tid;
        ridx[tid] = sorted[e * NROWS + (g < n_e ? g : n_e - 1)];
    }
    __syncthreads();
    int wave = tid >> 6, lane = tid & 63, lq = lane >> 4, lr = lane & 15;
    int wm = wave & 1, wn = wave >> 1;        // 2 M-waves x 4 N-waves
    const unsigned short* W1 = c1t + e * (256 * 512);
    const unsigned short* W2 = c2t + e * (256 * 256);
    const unsigned short* W3 = c3t + e * (16 * 256);

    // ---- GEMM1: h = relu(A @ W1T + b1), K=512 in 8 chunks of 64 ----
    f32x4 acc[4][4] = {};
#pragma unroll 1
    for (int kt = 0; kt < 8; ++kt) {
        // stage A chunk [128 rows][64 k] (gathered rows)
#pragma unroll
        for (int it = 0; it < 2; ++it) {
            int idx = it * 512 + tid;          // 1024 chunks of 16B
            int row = idx >> 3, slot = idx & 7;
            uint4v v = *(const uint4v*)(joined + (size_t)ridx[row] * 512 + kt * 64 + slot * 8);
            *(uint4v*)&Ast[row * 64 + (slot ^ (row & 7)) * 8] = v;
        }
        // stage B chunk [256 n][64 k]
#pragma unroll
        for (int it = 0; it < 4; ++it) {
            int idx = it * 512 + tid;          // 2048 chunks of 16B
            int n = idx >> 3, slot = idx & 7;
            uint4v v = *(const uint4v*)(W1 + (size_t)n * 512 + kt * 64 + slot * 8);
            *(uint4v*)&Bst[n * 64 + (slot ^ (n & 7)) * 8] = v;
        }
        __syncthreads();
#pragma unroll
        for (int ks = 0; ks < 2; ++ks) {
            bfx8 a[4], b[4];
#pragma unroll
            for (int mt = 0; mt < 4; ++mt) {
                int row = wm * 64 + mt * 16 + lr;
                a[mt] = *(const bfx8*)&Ast[row * 64 + ((ks * 32 + lq * 8) ^ ((row & 7) << 3))];
            }
#pragma unroll
            for (int nt = 0; nt < 4; ++nt) {
                int n = wn * 64 + nt * 16 + lr;
                b[nt] = *(const bfx8*)&Bst[n * 64 + ((ks * 32 + lq * 8) ^ ((n & 7) << 3))];
            }
#pragma unroll
            for (int mt = 0; mt < 4; ++mt)
#pragma unroll
                for (int nt = 0; nt < 4; ++nt)
                    acc[mt][nt] = mfma16(a[mt], b[nt], acc[mt][nt]);
        }
        __syncthreads();
    }
    // write h to LDS (bias+relu)
#pragma unroll
    for (int mt = 0; mt < 4; ++mt)
#pragma unroll
        for (int nt = 0; nt < 4; ++nt)
#pragma unroll
            for (int j = 0; j < 4; ++j) {
                int row = wm * 64 + mt * 16 + lq * 4 + j;
                int col = wn * 64 + nt * 16 + lr;
                float v = acc[mt][nt][j] + b1[e * 256 + col];
                v = v > 0.f ? v : 0.f;
                hls[row * 256 + swz(row, col)] = f2bf(v);
            }
    __syncthreads();

    // ---- GEMM2: h2 = relu(h @ W2T + b2), K=256 in 4 chunks of 64 ----
    f32x4 acc2[4][4] = {};
#pragma unroll 1
    for (int kt = 0; kt < 4; ++kt) {
#pragma unroll
        for (int it = 0; it < 4; ++it) {
            int idx = it * 512 + tid;
            int n = idx >> 3, slot = idx & 7;
            uint4v v = *(const uint4v*)(W2 + (size_t)n * 256 + kt * 64 + slot * 8);
            *(uint4v*)&Bst[n * 64 + (slot ^ (n & 7)) * 8] = v;
        }
        __syncthreads();
#pragma unroll
        for (int ks = 0; ks < 2; ++ks) {
            bfx8 a[4], b[4];
#pragma unroll
            for (int mt = 0; mt < 4; ++mt) {
                int row = wm * 64 + mt * 16 + lr;
                a[mt] = *(const bfx8*)&hls[row * 256 + swz(row, kt * 64 + ks * 32 + lq * 8)];
            }
#pragma unroll
            for (int nt = 0; nt < 4; ++nt) {
                int n = wn * 64 + nt * 16 + lr;
                b[nt] = *(const bfx8*)&Bst[n * 64 + ((ks * 32 + lq * 8) ^ ((n & 7) << 3))];
            }
#pragma unroll
            for (int mt = 0; mt < 4; ++mt)
#pragma unroll
                for (int nt = 0; nt < 4; ++nt)
                    acc2[mt][nt] = mfma16(a[mt], b[nt], acc2[mt][nt]);
        }
        __syncthreads();
    }
    // write h2 back into hls (bias+relu); all reads of h are done (last barrier above)
#pragma unroll
    for (int mt = 0; mt < 4; ++mt)
#pragma unroll
        for (int nt = 0; nt < 4; ++nt)
#pragma unroll
            for (int j = 0; j < 4; ++j) {
                int row = wm * 64 + mt * 16 + lq * 4 + j;
                int col = wn * 64 + nt * 16 + lr;
                float v = acc2[mt][nt][j] + b2[e * 256 + col];
                v = v > 0.f ? v : 0.f;
                hls[row * 256 + swz(row, col)] = f2bf(v);
            }
    __syncthreads();

    // ---- GEMM3: a = h2 @ W3T(pad N=16) + b3; each wave owns 16 rows; cols 0..2 valid ----
    {
        f32x4 acc3 = {};
#pragma unroll
        for (int ks = 0; ks < 8; ++ks) {
            int row = wave * 16 + lr;
            bfx8 a = *(const bfx8*)&hls[row * 256 + swz(row, ks * 32 + lq * 8)];
            bfx8 b = *(const bfx8*)(W3 + lr * 256 + ks * 32 + lq * 8);
            acc3 = mfma16(a, b, acc3);
        }
#pragma unroll
        for (int j = 0; j < 4; ++j) {
            int row = wave * 16 + lq * 4 + j;
            int g = i * 128 + row;
            if (lr < 3 && g < n_e)
                out_act[(size_t)ridx[row] * 3 + lr] = acc3[j] + b3[e * 3 + lr];
        }
    }
}

// ---------- launch ----------
extern "C" void kernel_launch(void* const* d_in, const int* in_sizes, int n_in,
                              void* d_out, int out_size, void* d_ws, size_t ws_size,
                              hipStream_t stream) {
    (void)in_sizes; (void)n_in; (void)out_size;
    if (ws_size < WS_NEED) return;

    const float* p_i    = (const float*)d_in[0];
    const float* speed  = (const float*)d_in[1];
    const int*   command= (const int*)d_in[2];
    const float* sp_W1  = (const float*)d_in[3];
    const float* sp_b1  = (const float*)d_in[4];
    const float* sp_W2  = (const float*)d_in[5];
    const float* sp_b2  = (const float*)d_in[6];
    const float* sp_W3  = (const float*)d_in[7];
    const float* sp_b3  = (const float*)d_in[8];
    const float* vp_W1  = (const float*)d_in[9];
    const float* vp_b1  = (const float*)d_in[10];
    const float* vp_W2  = (const float*)d_in[11];
    const float* vp_b2  = (const float*)d_in[12];
    const float* vp_W3  = (const float*)d_in[13];
    const float* vp_b3  = (const float*)d_in[14];
    const float* join_W = (const float*)d_in[15];
    const float* join_b = (const float*)d_in[16];
    const float* ctrl_W1= (const float*)d_in[17];
    const float* ctrl_b1= (const float*)d_in[18];
    const float* ctrl_W2= (const float*)d_in[19];
    const float* ctrl_b2= (const float*)d_in[20];
    const float* ctrl_W3= (const float*)d_in[21];
    const float* ctrl_b3= (const float*)d_in[22];

    char* ws = (char*)d_ws;
    unsigned short* Aaug   = (unsigned short*)(ws + A_AUG_B);
    unsigned short* joined = (unsigned short*)(ws + JOINED_B);
    unsigned short* g1     = (unsigned short*)(ws + G1_B);
    unsigned short* wct    = (unsigned short*)(ws + WCT_B);
    unsigned short* spw2t  = (unsigned short*)(ws + SPW2T_B);
    unsigned short* spw3t  = (unsigned short*)(ws + SPW3T_B);
    unsigned short* vpw2t  = (unsigned short*)(ws + VPW2T_B);
    unsigned short* vpw3t  = (unsigned short*)(ws + VPW3T_B);
    unsigned short* c1t    = (unsigned short*)(ws + C1T_B);
    unsigned short* c2t    = (unsigned short*)(ws + C2T_B);
    unsigned short* c3t    = (unsigned short*)(ws + C3T_B);
    int* cnt    = (int*)(ws + CNT_B);
    int* sorted = (int*)(ws + SORTED_B);

    float* out_vp  = (float*)d_out;          // output dtype is FLOAT32
    float* out_act = out_vp + NROWS;

    k_prep<<<1234, 256, 0, stream>>>(join_W, vp_W1, sp_W2, sp_W3, vp_W2, vp_W3,
                                     ctrl_W1, ctrl_W2, ctrl_W3,
                                     wct, spw2t, spw3t, vpw2t, vpw3t, c1t, c2t, c3t, cnt);
    k_sp_convert<<<256, 256, 0, stream>>>(p_i, speed, sp_W1, sp_b1, sp_b2, sp_b3,
                                          spw2t, spw3t, Aaug);
    k_scatter<<<128, 256, 0, stream>>>(command, cnt, sorted);
    k_join<<<1280, 256, 0, stream>>>(Aaug, wct, join_b, vp_b1, joined, g1);
    k_vp<<<256, 256, 0, stream>>>(g1, vpw2t, vpw3t, vp_b2, vp_b3, out_vp);
    k_ctrl<<<1024, 512, 0, stream>>>(joined, c1t, c2t, c3t, ctrl_b1, ctrl_b2, ctrl_b3,
                                     cnt, sorted, out_act);
}

// Round 8
// 277.951 us; speedup vs baseline: 1.5022x; 1.0957x over previous
//
#include <hip/hip_runtime.h>
#include <stdint.h>

#define NROWS 32768

typedef float f32x4 __attribute__((ext_vector_type(4)));
typedef __bf16 bfx8 __attribute__((ext_vector_type(8)));
typedef unsigned uint4v __attribute__((ext_vector_type(4)));

// ---------- helpers ----------
static __device__ __forceinline__ unsigned short f2bf(float f) {
    unsigned u = __builtin_bit_cast(unsigned, f);
    u += 0x7fffu + ((u >> 16) & 1u);   // RNE
    return (unsigned short)(u >> 16);
}

static __device__ __forceinline__ uint4v cvt8(f32x4 a, f32x4 b) {
    union { __bf16 h[8]; uint4v u; } p;
#pragma unroll
    for (int i = 0; i < 4; ++i) { p.h[i] = (__bf16)a[i]; p.h[4 + i] = (__bf16)b[i]; }
    return p.u;
}

static __device__ __forceinline__ f32x4 mfma16(bfx8 a, bfx8 b, f32x4 c) {
    return __builtin_amdgcn_mfma_f32_16x16x32_bf16(a, b, c, 0, 0, 0);
}

// XOR swizzle of column index (elements, bf16): permutes 16B slots within 8-slot groups
static __device__ __forceinline__ int swz(int row, int col) {
    return col ^ ((row & 7) << 3);
}

// ---------- workspace layout (bytes) ----------
static constexpr size_t JOINED_B = 0;            // [32768][512] bf16 = 33,554,432
static constexpr size_t V_B      = 33554432;     // [32768][128] bf16 =  8,388,608
static constexpr size_t WCT_B    = 41943040;     // [640][640] bf16   =    819,200
static constexpr size_t SPW2T_B  = 42762240;     // [128][128] bf16   =     32,768
static constexpr size_t SPW3T_B  = 42795008;     //                         32,768
static constexpr size_t VPW2T_B  = 42827776;     //                         32,768
static constexpr size_t VPW3T_B  = 42860544;     // [16][128] bf16    =      4,096
static constexpr size_t C1T_B    = 42864640;     // [4][256][512] bf16=  1,048,576
static constexpr size_t C2T_B    = 43913216;     // [4][256][256] bf16=    524,288
static constexpr size_t C3T_B    = 44437504;     // [4][16][256] bf16 =     32,768
static constexpr size_t CNT_B    = 44470272;     // 16 ints           =         64
static constexpr size_t SORTED_B = 44470336;     // [4][32768] int    =    524,288
static constexpr size_t WS_NEED  = 44994624;

// ---------- K0: weight transpose/convert (source-major: coalesced loads, scattered stores) ----------
__global__ __launch_bounds__(256) void k_prep(
    const float* joinW, const float* vpW1, const float* spW2, const float* spW3,
    const float* vpW2, const float* vpW3, const float* c1, const float* c2, const float* c3,
    unsigned short* wct, unsigned short* spw2t, unsigned short* spw3t,
    unsigned short* vpw2t, unsigned short* vpw3t,
    unsigned short* c1t, unsigned short* c2t, unsigned short* c3t, int* cnt)
{
    int bid = blockIdx.x, tid = threadIdx.x;
    if (bid == 0 && tid < 16) cnt[tid] = 0;
    int region, s0;
    if      (bid < 256)  { region = 0; s0 = bid * 1024; }          // wct <- joinW (262144)
    else if (bid < 320)  { region = 1; s0 = (bid - 256) * 1024; }  // wct <- vpW1 (65536)
    else if (bid < 336)  { region = 2; s0 = (bid - 320) * 1024; }  // wct zero pad (16384)
    else if (bid < 352)  { region = 3; s0 = (bid - 336) * 1024; }  // spw2t (16384)
    else if (bid < 368)  { region = 4; s0 = (bid - 352) * 1024; }  // spw3t (16384)
    else if (bid < 384)  { region = 5; s0 = (bid - 368) * 1024; }  // vpw2t (16384)
    else if (bid < 386)  { region = 6; s0 = (bid - 384) * 1024; }  // vpw3t (2048)
    else if (bid < 898)  { region = 7; s0 = (bid - 386) * 1024; }  // c1t (524288)
    else if (bid < 1154) { region = 8; s0 = (bid - 898) * 1024; }  // c2t (262144)
    else                 { region = 9; s0 = (bid - 1154) * 1024; } // c3t dest-major (16384)
    for (int j = 0; j < 4; ++j) {
        int s = s0 + tid + j * 256;
        switch (region) {
        case 0: { int k = s >> 9, n = s & 511; wct[n * 640 + k] = f2bf(joinW[s]); } break;
        case 1: { int k = s >> 7, n = s & 127; wct[(512 + n) * 640 + k] = f2bf(vpW1[s]); } break;
        case 2: { int n = 512 + (s >> 7), k = 512 + (s & 127); wct[n * 640 + k] = 0; } break;
        case 3: { int k = s >> 7, n = s & 127; spw2t[n * 128 + k] = f2bf(spW2[s]); } break;
        case 4: { int k = s >> 7, n = s & 127; spw3t[n * 128 + k] = f2bf(spW3[s]); } break;
        case 5: { int k = s >> 7, n = s & 127; vpw2t[n * 128 + k] = f2bf(vpW2[s]); } break;
        case 6: { vpw3t[s] = (s < 128) ? f2bf(vpW3[s]) : 0; } break;
        case 7: { int e = s >> 17, k = (s >> 8) & 511, n = s & 255;
                  c1t[e * 131072 + n * 512 + k] = f2bf(c1[s]); } break;
        case 8: { int e = s >> 16, k = (s >> 8) & 255, n = s & 255;
                  c2t[e * 65536 + n * 256 + k] = f2bf(c2[s]); } break;
        case 9: { int e = s >> 12, r = s & 4095, n = r >> 8, k = r & 255;
                  c3t[s] = (n < 3) ? f2bf(c3[e * 768 + k * 3 + n]) : 0; } break;
        }
    }
}

// ---------- K1: sp-MLP (speed -> v[32768][128]) + command scatter fused ----------
__global__ __launch_bounds__(256) void k_sp(
    const float* speed, const float* spW1, const float* spb1,
    const float* spb2, const float* spb3,
    const unsigned short* spw2t, const unsigned short* spw3t,
    const int* command, int* cnt, int* sorted, unsigned short* v)
{
    __shared__ alignas(16) unsigned short h1[128 * 128];  // swizzled
    __shared__ alignas(16) unsigned short h2[128 * 128];  // swizzled
    __shared__ int lcnt[4], lbase[4];
    int bid = blockIdx.x, tid = threadIdx.x;
    int r0 = bid * 128;

    // ---- scatter (128 rows/block) ----
    if (tid < 4) lcnt[tid] = 0;
    __syncthreads();
    int cc = 0, lpos = 0;
    if (tid < 128) { cc = command[r0 + tid] & 3; lpos = atomicAdd(&lcnt[cc], 1); }
    __syncthreads();
    if (tid < 4) lbase[tid] = atomicAdd(&cnt[tid], lcnt[tid]);
    __syncthreads();
    if (tid < 128) sorted[cc * NROWS + lbase[cc] + lpos] = r0 + tid;

    // ---- h1 = relu(speed*W1 + b1) ----
    for (int j = 0; j < 64; ++j) {
        int idx = tid + j * 256;
        int row = idx >> 7, col = idx & 127;
        float h = speed[r0 + row] * spW1[col] + spb1[col];
        h = h > 0.f ? h : 0.f;
        h1[row * 128 + swz(row, col)] = f2bf(h);
    }
    __syncthreads();

    int wave = tid >> 6, lane = tid & 63, lq = lane >> 4, lr = lane & 15;
    int wr = wave >> 1, wc = wave & 1;
    // GEMM1: h2 = relu(h1 @ spW2T + b2)
    f32x4 acc[4][4] = {};
#pragma unroll
    for (int ks = 0; ks < 4; ++ks) {
        bfx8 a[4], b[4];
#pragma unroll
        for (int mt = 0; mt < 4; ++mt) {
            int row = wr * 64 + mt * 16 + lr;
            a[mt] = *(const bfx8*)&h1[row * 128 + swz(row, ks * 32 + lq * 8)];
        }
#pragma unroll
        for (int nt = 0; nt < 4; ++nt) {
            int n = wc * 64 + nt * 16 + lr;
            b[nt] = *(const bfx8*)(spw2t + n * 128 + ks * 32 + lq * 8);
        }
#pragma unroll
        for (int mt = 0; mt < 4; ++mt)
#pragma unroll
            for (int nt = 0; nt < 4; ++nt)
                acc[mt][nt] = mfma16(a[mt], b[nt], acc[mt][nt]);
    }
#pragma unroll
    for (int mt = 0; mt < 4; ++mt)
#pragma unroll
        for (int nt = 0; nt < 4; ++nt)
#pragma unroll
            for (int j = 0; j < 4; ++j) {
                int row = wr * 64 + mt * 16 + lq * 4 + j;
                int col = wc * 64 + nt * 16 + lr;
                float x = acc[mt][nt][j] + spb2[col];
                x = x > 0.f ? x : 0.f;
                h2[row * 128 + swz(row, col)] = f2bf(x);
            }
    __syncthreads();
    // GEMM2: v = h2 @ spW3T + b3 (no relu) -> v global
    f32x4 acc2[4][4] = {};
#pragma unroll
    for (int ks = 0; ks < 4; ++ks) {
        bfx8 a[4], b[4];
#pragma unroll
        for (int mt = 0; mt < 4; ++mt) {
            int row = wr * 64 + mt * 16 + lr;
            a[mt] = *(const bfx8*)&h2[row * 128 + swz(row, ks * 32 + lq * 8)];
        }
#pragma unroll
        for (int nt = 0; nt < 4; ++nt) {
            int n = wc * 64 + nt * 16 + lr;
            b[nt] = *(const bfx8*)(spw3t + n * 128 + ks * 32 + lq * 8);
        }
#pragma unroll
        for (int mt = 0; mt < 4; ++mt)
#pragma unroll
            for (int nt = 0; nt < 4; ++nt)
                acc2[mt][nt] = mfma16(a[mt], b[nt], acc2[mt][nt]);
    }
#pragma unroll
    for (int mt = 0; mt < 4; ++mt)
#pragma unroll
        for (int nt = 0; nt < 4; ++nt)
#pragma unroll
            for (int j = 0; j < 4; ++j) {
                int row = wr * 64 + mt * 16 + lq * 4 + j;
                int col = wc * 64 + nt * 16 + lr;
                v[(size_t)(r0 + row) * 128 + col] = f2bf(acc2[mt][nt][j] + spb3[col]);
            }
}

// ---------- K2: joined = [bf16(p_i) | v] @ WcT; vp-tail fused on n0==512 blocks ----------
__global__ __launch_bounds__(256) void k_join(
    const float* p_i, const unsigned short* v, const unsigned short* wct,
    const float* joinb, const float* vpb1,
    const unsigned short* vpw2t, const unsigned short* vpw3t,
    const float* vpb2, const float* vpb3,
    unsigned short* joined, float* out_vp)
{
    __shared__ alignas(16) unsigned short stg[16384];   // At [0,8192) | Bt [8192,16384); vp reuses all
    int d = blockIdx.x;
    int L = (d & 7) * 160 + (d >> 3);       // XCD swizzle (1280 % 8 == 0, bijective)
    int m0 = (L / 5) * 128, n0 = (L % 5) * 128;
    int tid = threadIdx.x, wave = tid >> 6, lane = tid & 63, lq = lane >> 4, lr = lane & 15;
    int wr = wave >> 1, wc = wave & 1;

    // staging geometry: thread owns rows r0t+{0,32,64,96}, slot s0t; swizzled slot invariant.
    int r0t = tid >> 3, s0t = tid & 7;
    int ss = s0t ^ (r0t & 7);
    const float* pA = p_i + (size_t)(m0 + r0t) * 512 + s0t * 8;
    const unsigned short* pAv = v + (size_t)(m0 + r0t) * 128 + s0t * 8;
    const unsigned short* pB = wct + (size_t)(n0 + r0t) * 640 + s0t * 8;
    unsigned short* lA = &stg[r0t * 64 + ss * 8];
    unsigned short* lB = &stg[8192 + r0t * 64 + ss * 8];

    f32x4 raf[4][2];
    uint4v rab[4], rb[4];
#pragma unroll
    for (int c2 = 0; c2 < 4; ++c2) {        // prologue: chunk 0
        raf[c2][0] = *(const f32x4*)(pA + c2 * 16384);
        raf[c2][1] = *(const f32x4*)(pA + c2 * 16384 + 4);
        rb[c2]     = *(const uint4v*)(pB + c2 * 20480);
    }
    f32x4 acc[4][4] = {};
#pragma unroll 1
    for (int kt = 0; kt < 10; ++kt) {
        if (kt < 8) {
#pragma unroll
            for (int c2 = 0; c2 < 4; ++c2)
                *(uint4v*)(lA + c2 * 2048) = cvt8(raf[c2][0], raf[c2][1]);
        } else {
#pragma unroll
            for (int c2 = 0; c2 < 4; ++c2)
                *(uint4v*)(lA + c2 * 2048) = rab[c2];
        }
#pragma unroll
        for (int c2 = 0; c2 < 4; ++c2)
            *(uint4v*)(lB + c2 * 2048) = rb[c2];
        __syncthreads();
        if (kt < 7) {                        // prefetch next f32 chunk
#pragma unroll
            for (int c2 = 0; c2 < 4; ++c2) {
                raf[c2][0] = *(const f32x4*)(pA + c2 * 16384 + (kt + 1) * 64);
                raf[c2][1] = *(const f32x4*)(pA + c2 * 16384 + (kt + 1) * 64 + 4);
            }
        } else if (kt < 9) {                 // prefetch v chunk (kt+1 in {8,9})
#pragma unroll
            for (int c2 = 0; c2 < 4; ++c2)
                rab[c2] = *(const uint4v*)(pAv + c2 * 4096 + (kt + 1 - 8) * 64);
        }
        if (kt < 9) {
#pragma unroll
            for (int c2 = 0; c2 < 4; ++c2)
                rb[c2] = *(const uint4v*)(pB + c2 * 20480 + (kt + 1) * 64);
        }
#pragma unroll
        for (int ks = 0; ks < 2; ++ks) {
            bfx8 a[4], b[4];
#pragma unroll
            for (int mt = 0; mt < 4; ++mt) {
                int row = wr * 64 + mt * 16 + lr;
                a[mt] = *(const bfx8*)&stg[row * 64 + ((ks * 32 + lq * 8) ^ ((row & 7) << 3))];
            }
#pragma unroll
            for (int nt = 0; nt < 4; ++nt) {
                int n = wc * 64 + nt * 16 + lr;
                b[nt] = *(const bfx8*)&stg[8192 + n * 64 + ((ks * 32 + lq * 8) ^ ((n & 7) << 3))];
            }
#pragma unroll
            for (int mt = 0; mt < 4; ++mt)
#pragma unroll
                for (int nt = 0; nt < 4; ++nt)
                    acc[mt][nt] = mfma16(a[mt], b[nt], acc[mt][nt]);
        }
        __syncthreads();
    }

    if (n0 < 512) {
        // plain joined tile
#pragma unroll
        for (int mt = 0; mt < 4; ++mt)
#pragma unroll
            for (int nt = 0; nt < 4; ++nt)
#pragma unroll
                for (int j = 0; j < 4; ++j) {
                    int row = m0 + wr * 64 + mt * 16 + lq * 4 + j;
                    int col = n0 + wc * 64 + nt * 16 + lr;
                    joined[(size_t)row * 512 + col] = f2bf(acc[mt][nt][j] + joinb[col]);
                }
        return;
    }

    // ---- n0==512: this block holds g1 = relu(acc + vpb1) for its 128 rows -> fused vp tail ----
#pragma unroll
    for (int mt = 0; mt < 4; ++mt)
#pragma unroll
        for (int nt = 0; nt < 4; ++nt)
#pragma unroll
            for (int j = 0; j < 4; ++j) {
                int row = wr * 64 + mt * 16 + lq * 4 + j;
                int col = wc * 64 + nt * 16 + lr;
                float x = acc[mt][nt][j] + vpb1[col];
                x = x > 0.f ? x : 0.f;
                stg[row * 128 + swz(row, col)] = f2bf(x);
            }
    __syncthreads();
    // vp GEMM1: h2 = relu(g @ vpW2T + b2), K=128
    f32x4 acc2[4][4] = {};
#pragma unroll
    for (int ks = 0; ks < 4; ++ks) {
        bfx8 a[4], b[4];
#pragma unroll
        for (int mt = 0; mt < 4; ++mt) {
            int row = wr * 64 + mt * 16 + lr;
            a[mt] = *(const bfx8*)&stg[row * 128 + swz(row, ks * 32 + lq * 8)];
        }
#pragma unroll
        for (int nt = 0; nt < 4; ++nt) {
            int n = wc * 64 + nt * 16 + lr;
            b[nt] = *(const bfx8*)(vpw2t + n * 128 + ks * 32 + lq * 8);
        }
#pragma unroll
        for (int mt = 0; mt < 4; ++mt)
#pragma unroll
            for (int nt = 0; nt < 4; ++nt)
                acc2[mt][nt] = mfma16(a[mt], b[nt], acc2[mt][nt]);
    }
    __syncthreads();   // all g reads done before overwrite
#pragma unroll
    for (int mt = 0; mt < 4; ++mt)
#pragma unroll
        for (int nt = 0; nt < 4; ++nt)
#pragma unroll
            for (int j = 0; j < 4; ++j) {
                int row = wr * 64 + mt * 16 + lq * 4 + j;
                int col = wc * 64 + nt * 16 + lr;
                float x = acc2[mt][nt][j] + vpb2[col];
                x = x > 0.f ? x : 0.f;
                stg[row * 128 + swz(row, col)] = f2bf(x);
            }
    __syncthreads();
    // vp GEMM2: v_p = h2 @ vpW3T(pad N=16) + b3; col 0 valid
    f32x4 acc3[2] = {};
#pragma unroll
    for (int ks = 0; ks < 4; ++ks) {
        bfx8 b = *(const bfx8*)(vpw3t + lr * 128 + ks * 32 + lq * 8);
#pragma unroll
        for (int mt = 0; mt < 2; ++mt) {
            int row = wave * 32 + mt * 16 + lr;
            bfx8 a = *(const bfx8*)&stg[row * 128 + swz(row, ks * 32 + lq * 8)];
            acc3[mt] = mfma16(a, b, acc3[mt]);
        }
    }
    if (lr == 0) {
#pragma unroll
        for (int mt = 0; mt < 2; ++mt)
#pragma unroll
            for (int j = 0; j < 4; ++j) {
                int row = wave * 32 + mt * 16 + lq * 4 + j;
                out_vp[m0 + row] = acc3[mt][j] + vpb3[0];
            }
    }
}

// ---------- K3: routed control heads, LDS-staged GEMM (M=128/block, N=256, f32 out) ----------
__global__ __launch_bounds__(512) void k_ctrl(
    const unsigned short* joined, const unsigned short* c1t, const unsigned short* c2t,
    const unsigned short* c3t, const float* b1, const float* b2, const float* b3,
    const int* cnt, const int* sorted, float* out_act)
{
    __shared__ alignas(16) unsigned short hls[128 * 256];  // h, then h2 (swizzled)
    __shared__ alignas(16) unsigned short Ast[128 * 64];   // A K-chunk (swizzled)
    __shared__ alignas(16) unsigned short Bst[256 * 64];   // W K-chunk (swizzled)
    __shared__ int ridx[128];
    int bid = blockIdx.x;
    int e = bid >> 8, i = bid & 255;
    int n_e = cnt[e];
    if (i * 128 >= n_e) return;
    int tid = threadIdx.x;
    if (tid < 128) {
        int g = i * 128 + tid;
        ridx[tid] = sorted[e * NROWS + (g < n_e ? g : n_e - 1)];
    }
    __syncthreads();
    int wave = tid >> 6, lane = tid & 63, lq = lane >> 4, lr = lane & 15;
    int wm = wave & 1, wn = wave >> 1;        // 2 M-waves x 4 N-waves
    const unsigned short* W1 = c1t + e * (256 * 512);
    const unsigned short* W2 = c2t + e * (256 * 256);
    const unsigned short* W3 = c3t + e * (16 * 256);

    // ---- GEMM1: h = relu(A @ W1T + b1), K=512 in 8 chunks of 64 ----
    f32x4 acc[4][4] = {};
#pragma unroll 1
    for (int kt = 0; kt < 8; ++kt) {
#pragma unroll
        for (int it = 0; it < 2; ++it) {
            int idx = it * 512 + tid;          // 1024 chunks of 16B
            int row = idx >> 3, slot = idx & 7;
            uint4v v = *(const uint4v*)(joined + (size_t)ridx[row] * 512 + kt * 64 + slot * 8);
            *(uint4v*)&Ast[row * 64 + (slot ^ (row & 7)) * 8] = v;
        }
#pragma unroll
        for (int it = 0; it < 4; ++it) {
            int idx = it * 512 + tid;          // 2048 chunks of 16B
            int n = idx >> 3, slot = idx & 7;
            uint4v v = *(const uint4v*)(W1 + (size_t)n * 512 + kt * 64 + slot * 8);
            *(uint4v*)&Bst[n * 64 + (slot ^ (n & 7)) * 8] = v;
        }
        __syncthreads();
#pragma unroll
        for (int ks = 0; ks < 2; ++ks) {
            bfx8 a[4], b[4];
#pragma unroll
            for (int mt = 0; mt < 4; ++mt) {
                int row = wm * 64 + mt * 16 + lr;
                a[mt] = *(const bfx8*)&Ast[row * 64 + ((ks * 32 + lq * 8) ^ ((row & 7) << 3))];
            }
#pragma unroll
            for (int nt = 0; nt < 4; ++nt) {
                int n = wn * 64 + nt * 16 + lr;
                b[nt] = *(const bfx8*)&Bst[n * 64 + ((ks * 32 + lq * 8) ^ ((n & 7) << 3))];
            }
#pragma unroll
            for (int mt = 0; mt < 4; ++mt)
#pragma unroll
                for (int nt = 0; nt < 4; ++nt)
                    acc[mt][nt] = mfma16(a[mt], b[nt], acc[mt][nt]);
        }
        __syncthreads();
    }
#pragma unroll
    for (int mt = 0; mt < 4; ++mt)
#pragma unroll
        for (int nt = 0; nt < 4; ++nt)
#pragma unroll
            for (int j = 0; j < 4; ++j) {
                int row = wm * 64 + mt * 16 + lq * 4 + j;
                int col = wn * 64 + nt * 16 + lr;
                float x = acc[mt][nt][j] + b1[e * 256 + col];
                x = x > 0.f ? x : 0.f;
                hls[row * 256 + swz(row, col)] = f2bf(x);
            }
    __syncthreads();

    // ---- GEMM2: h2 = relu(h @ W2T + b2), K=256 in 4 chunks of 64 ----
    f32x4 acc2[4][4] = {};
#pragma unroll 1
    for (int kt = 0; kt < 4; ++kt) {
#pragma unroll
        for (int it = 0; it < 4; ++it) {
            int idx = it * 512 + tid;
            int n = idx >> 3, slot = idx & 7;
            uint4v v = *(const uint4v*)(W2 + (size_t)n * 256 + kt * 64 + slot * 8);
            *(uint4v*)&Bst[n * 64 + (slot ^ (n & 7)) * 8] = v;
        }
        __syncthreads();
#pragma unroll
        for (int ks = 0; ks < 2; ++ks) {
            bfx8 a[4], b[4];
#pragma unroll
            for (int mt = 0; mt < 4; ++mt) {
                int row = wm * 64 + mt * 16 + lr;
                a[mt] = *(const bfx8*)&hls[row * 256 + swz(row, kt * 64 + ks * 32 + lq * 8)];
            }
#pragma unroll
            for (int nt = 0; nt < 4; ++nt) {
                int n = wn * 64 + nt * 16 + lr;
                b[nt] = *(const bfx8*)&Bst[n * 64 + ((ks * 32 + lq * 8) ^ ((n & 7) << 3))];
            }
#pragma unroll
            for (int mt = 0; mt < 4; ++mt)
#pragma unroll
                for (int nt = 0; nt < 4; ++nt)
                    acc2[mt][nt] = mfma16(a[mt], b[nt], acc2[mt][nt]);
        }
        __syncthreads();
    }
#pragma unroll
    for (int mt = 0; mt < 4; ++mt)
#pragma unroll
        for (int nt = 0; nt < 4; ++nt)
#pragma unroll
            for (int j = 0; j < 4; ++j) {
                int row = wm * 64 + mt * 16 + lq * 4 + j;
                int col = wn * 64 + nt * 16 + lr;
                float x = acc2[mt][nt][j] + b2[e * 256 + col];
                x = x > 0.f ? x : 0.f;
                hls[row * 256 + swz(row, col)] = f2bf(x);
            }
    __syncthreads();

    // ---- GEMM3: a = h2 @ W3T(pad N=16) + b3; each wave owns 16 rows; cols 0..2 valid ----
    {
        f32x4 acc3 = {};
#pragma unroll
        for (int ks = 0; ks < 8; ++ks) {
            int row = wave * 16 + lr;
            bfx8 a = *(const bfx8*)&hls[row * 256 + swz(row, ks * 32 + lq * 8)];
            bfx8 b = *(const bfx8*)(W3 + lr * 256 + ks * 32 + lq * 8);
            acc3 = mfma16(a, b, acc3);
        }
#pragma unroll
        for (int j = 0; j < 4; ++j) {
            int row = wave * 16 + lq * 4 + j;
            int g = i * 128 + row;
            if (lr < 3 && g < n_e)
                out_act[(size_t)ridx[row] * 3 + lr] = acc3[j] + b3[e * 3 + lr];
        }
    }
}

// ---------- launch ----------
extern "C" void kernel_launch(void* const* d_in, const int* in_sizes, int n_in,
                              void* d_out, int out_size, void* d_ws, size_t ws_size,
                              hipStream_t stream) {
    (void)in_sizes; (void)n_in; (void)out_size;
    if (ws_size < WS_NEED) return;

    const float* p_i    = (const float*)d_in[0];
    const float* speed  = (const float*)d_in[1];
    const int*   command= (const int*)d_in[2];
    const float* sp_W1  = (const float*)d_in[3];
    const float* sp_b1  = (const float*)d_in[4];
    const float* sp_W2  = (const float*)d_in[5];
    const float* sp_b2  = (const float*)d_in[6];
    const float* sp_W3  = (const float*)d_in[7];
    const float* sp_b3  = (const float*)d_in[8];
    const float* vp_W1  = (const float*)d_in[9];
    const float* vp_b1  = (const float*)d_in[10];
    const float* vp_W2  = (const float*)d_in[11];
    const float* vp_b2  = (const float*)d_in[12];
    const float* vp_W3  = (const float*)d_in[13];
    const float* vp_b3  = (const float*)d_in[14];
    const float* join_W = (const float*)d_in[15];
    const float* join_b = (const float*)d_in[16];
    const float* ctrl_W1= (const float*)d_in[17];
    const float* ctrl_b1= (const float*)d_in[18];
    const float* ctrl_W2= (const float*)d_in[19];
    const float* ctrl_b2= (const float*)d_in[20];
    const float* ctrl_W3= (const float*)d_in[21];
    const float* ctrl_b3= (const float*)d_in[22];

    char* ws = (char*)d_ws;
    unsigned short* joined = (unsigned short*)(ws + JOINED_B);
    unsigned short* vbuf   = (unsigned short*)(ws + V_B);
    unsigned short* wct    = (unsigned short*)(ws + WCT_B);
    unsigned short* spw2t  = (unsigned short*)(ws + SPW2T_B);
    unsigned short* spw3t  = (unsigned short*)(ws + SPW3T_B);
    unsigned short* vpw2t  = (unsigned short*)(ws + VPW2T_B);
    unsigned short* vpw3t  = (unsigned short*)(ws + VPW3T_B);
    unsigned short* c1t    = (unsigned short*)(ws + C1T_B);
    unsigned short* c2t    = (unsigned short*)(ws + C2T_B);
    unsigned short* c3t    = (unsigned short*)(ws + C3T_B);
    int* cnt    = (int*)(ws + CNT_B);
    int* sorted = (int*)(ws + SORTED_B);

    float* out_vp  = (float*)d_out;          // output dtype FLOAT32
    float* out_act = out_vp + NROWS;

    k_prep<<<1170, 256, 0, stream>>>(join_W, vp_W1, sp_W2, sp_W3, vp_W2, vp_W3,
                                     ctrl_W1, ctrl_W2, ctrl_W3,
                                     wct, spw2t, spw3t, vpw2t, vpw3t, c1t, c2t, c3t, cnt);
    k_sp<<<256, 256, 0, stream>>>(speed, sp_W1, sp_b1, sp_b2, sp_b3,
                                  spw2t, spw3t, command, cnt, sorted, vbuf);
    k_join<<<1280, 256, 0, stream>>>(p_i, vbuf, wct, join_b, vp_b1,
                                     vpw2t, vpw3t, vp_b2, vp_b3, joined, out_vp);
    k_ctrl<<<1024, 512, 0, stream>>>(joined, c1t, c2t, c3t, ctrl_b1, ctrl_b2, ctrl_b3,
                                     cnt, sorted, out_act);
}

// Round 9
// 274.176 us; speedup vs baseline: 1.5229x; 1.0138x over previous
//
#include <hip/hip_runtime.h>
#include <stdint.h>

#define NROWS 32768

typedef float f32x4 __attribute__((ext_vector_type(4)));
typedef __bf16 bfx8 __attribute__((ext_vector_type(8)));
typedef unsigned uint4v __attribute__((ext_vector_type(4)));

// ---------- helpers ----------
static __device__ __forceinline__ unsigned short f2bf(float f) {
    unsigned u = __builtin_bit_cast(unsigned, f);
    u += 0x7fffu + ((u >> 16) & 1u);   // RNE
    return (unsigned short)(u >> 16);
}

static __device__ __forceinline__ f32x4 mfma16(bfx8 a, bfx8 b, f32x4 c) {
    return __builtin_amdgcn_mfma_f32_16x16x32_bf16(a, b, c, 0, 0, 0);
}

// async global->LDS, 16B per lane; LDS dest must be wave-uniform base (linear fill)
static __device__ __forceinline__ void gload_lds16(const void* g, void* l) {
    __builtin_amdgcn_global_load_lds(
        (const __attribute__((address_space(1))) void*)g,
        (__attribute__((address_space(3))) void*)l, 16, 0, 0);
}

// XOR swizzle of column index (elements, bf16): permutes 16B slots within 8-slot groups
static __device__ __forceinline__ int swz(int row, int col) {
    return col ^ ((row & 7) << 3);
}

// ---------- workspace layout (bytes) ----------
static constexpr size_t JOINED_B = 0;            // [32768][512] bf16 = 33,554,432
static constexpr size_t PI_B     = 33554432;     // [32768][512] bf16 = 33,554,432
static constexpr size_t V_B      = 67108864;     // [32768][128] bf16 =  8,388,608
static constexpr size_t WCT_B    = 75497472;     // [640][640] bf16   =    819,200
static constexpr size_t SPW2T_B  = 76316672;     // [128][128] bf16
static constexpr size_t SPW3T_B  = 76349440;
static constexpr size_t VPW2T_B  = 76382208;
static constexpr size_t VPW3T_B  = 76414976;     // [16][128] bf16
static constexpr size_t C1T_B    = 76419072;     // [4][256][512] bf16
static constexpr size_t C2T_B    = 77467648;     // [4][256][256] bf16
static constexpr size_t C3T_B    = 77991936;     // [4][16][256] bf16
static constexpr size_t CNT_B    = 78024704;     // 16 ints
static constexpr size_t SORTED_B = 78024768;     // [4][32768] int
static constexpr size_t WS_NEED  = 78549056;

// ---------- K0: p_i f32->bf16 (coalesced, layout-preserving) + weight transpose/convert ----------
__global__ __launch_bounds__(256) void k_prep(
    const float* p_i, const float* joinW, const float* vpW1, const float* spW2,
    const float* spW3, const float* vpW2, const float* vpW3,
    const float* c1, const float* c2, const float* c3,
    unsigned short* pib, unsigned short* wct, unsigned short* spw2t, unsigned short* spw3t,
    unsigned short* vpw2t, unsigned short* vpw3t,
    unsigned short* c1t, unsigned short* c2t, unsigned short* c3t, int* cnt)
{
    int bid = blockIdx.x, tid = threadIdx.x;
    if (bid == 0 && tid < 16) cnt[tid] = 0;
    if (bid < 4096) {
        // p_i conversion: 4,194,304 f32x4 chunks, 1024/block, fully coalesced both sides
        size_t c0 = (size_t)bid * 1024;
#pragma unroll
        for (int j = 0; j < 4; ++j) {
            size_t c = c0 + tid + j * 256;
            f32x4 x = *(const f32x4*)(p_i + c * 4);
            ushort4 o;
            o.x = f2bf(x[0]); o.y = f2bf(x[1]); o.z = f2bf(x[2]); o.w = f2bf(x[3]);
            *(ushort4*)(pib + c * 4) = o;
        }
        return;
    }
    int b = bid - 4096;
    int region, s0;
    if      (b < 256)  { region = 0; s0 = b * 1024; }          // wct <- joinW
    else if (b < 320)  { region = 1; s0 = (b - 256) * 1024; }  // wct <- vpW1
    else if (b < 336)  { region = 2; s0 = (b - 320) * 1024; }  // wct zero pad
    else if (b < 352)  { region = 3; s0 = (b - 336) * 1024; }  // spw2t
    else if (b < 368)  { region = 4; s0 = (b - 352) * 1024; }  // spw3t
    else if (b < 384)  { region = 5; s0 = (b - 368) * 1024; }  // vpw2t
    else if (b < 386)  { region = 6; s0 = (b - 384) * 1024; }  // vpw3t
    else if (b < 898)  { region = 7; s0 = (b - 386) * 1024; }  // c1t
    else if (b < 1154) { region = 8; s0 = (b - 898) * 1024; }  // c2t
    else               { region = 9; s0 = (b - 1154) * 1024; } // c3t
    for (int j = 0; j < 4; ++j) {
        int s = s0 + tid + j * 256;
        switch (region) {
        case 0: { int k = s >> 9, n = s & 511; wct[n * 640 + k] = f2bf(joinW[s]); } break;
        case 1: { int k = s >> 7, n = s & 127; wct[(512 + n) * 640 + k] = f2bf(vpW1[s]); } break;
        case 2: { int n = 512 + (s >> 7), k = 512 + (s & 127); wct[n * 640 + k] = 0; } break;
        case 3: { int k = s >> 7, n = s & 127; spw2t[n * 128 + k] = f2bf(spW2[s]); } break;
        case 4: { int k = s >> 7, n = s & 127; spw3t[n * 128 + k] = f2bf(spW3[s]); } break;
        case 5: { int k = s >> 7, n = s & 127; vpw2t[n * 128 + k] = f2bf(vpW2[s]); } break;
        case 6: { vpw3t[s] = (s < 128) ? f2bf(vpW3[s]) : 0; } break;
        case 7: { int e = s >> 17, k = (s >> 8) & 511, n = s & 255;
                  c1t[e * 131072 + n * 512 + k] = f2bf(c1[s]); } break;
        case 8: { int e = s >> 16, k = (s >> 8) & 255, n = s & 255;
                  c2t[e * 65536 + n * 256 + k] = f2bf(c2[s]); } break;
        case 9: { int e = s >> 12, r = s & 4095, n = r >> 8, k = r & 255;
                  c3t[s] = (n < 3) ? f2bf(c3[e * 768 + k * 3 + n]) : 0; } break;
        }
    }
}

// ---------- K1: sp-MLP (speed -> v[32768][128]) + command scatter fused ----------
__global__ __launch_bounds__(256) void k_sp(
    const float* speed, const float* spW1, const float* spb1,
    const float* spb2, const float* spb3,
    const unsigned short* spw2t, const unsigned short* spw3t,
    const int* command, int* cnt, int* sorted, unsigned short* v)
{
    __shared__ alignas(16) unsigned short h1[128 * 128];  // swizzled
    __shared__ alignas(16) unsigned short h2[128 * 128];  // swizzled
    __shared__ int lcnt[4], lbase[4];
    int bid = blockIdx.x, tid = threadIdx.x;
    int r0 = bid * 128;

    if (tid < 4) lcnt[tid] = 0;
    __syncthreads();
    int cc = 0, lpos = 0;
    if (tid < 128) { cc = command[r0 + tid] & 3; lpos = atomicAdd(&lcnt[cc], 1); }
    __syncthreads();
    if (tid < 4) lbase[tid] = atomicAdd(&cnt[tid], lcnt[tid]);
    __syncthreads();
    if (tid < 128) sorted[cc * NROWS + lbase[cc] + lpos] = r0 + tid;

    for (int j = 0; j < 64; ++j) {
        int idx = tid + j * 256;
        int row = idx >> 7, col = idx & 127;
        float h = speed[r0 + row] * spW1[col] + spb1[col];
        h = h > 0.f ? h : 0.f;
        h1[row * 128 + swz(row, col)] = f2bf(h);
    }
    __syncthreads();

    int wave = tid >> 6, lane = tid & 63, lq = lane >> 4, lr = lane & 15;
    int wr = wave >> 1, wc = wave & 1;
    f32x4 acc[4][4] = {};
#pragma unroll
    for (int ks = 0; ks < 4; ++ks) {
        bfx8 a[4], b[4];
#pragma unroll
        for (int mt = 0; mt < 4; ++mt) {
            int row = wr * 64 + mt * 16 + lr;
            a[mt] = *(const bfx8*)&h1[row * 128 + swz(row, ks * 32 + lq * 8)];
        }
#pragma unroll
        for (int nt = 0; nt < 4; ++nt) {
            int n = wc * 64 + nt * 16 + lr;
            b[nt] = *(const bfx8*)(spw2t + n * 128 + ks * 32 + lq * 8);
        }
#pragma unroll
        for (int mt = 0; mt < 4; ++mt)
#pragma unroll
            for (int nt = 0; nt < 4; ++nt)
                acc[mt][nt] = mfma16(a[mt], b[nt], acc[mt][nt]);
    }
#pragma unroll
    for (int mt = 0; mt < 4; ++mt)
#pragma unroll
        for (int nt = 0; nt < 4; ++nt)
#pragma unroll
            for (int j = 0; j < 4; ++j) {
                int row = wr * 64 + mt * 16 + lq * 4 + j;
                int col = wc * 64 + nt * 16 + lr;
                float x = acc[mt][nt][j] + spb2[col];
                x = x > 0.f ? x : 0.f;
                h2[row * 128 + swz(row, col)] = f2bf(x);
            }
    __syncthreads();
    f32x4 acc2[4][4] = {};
#pragma unroll
    for (int ks = 0; ks < 4; ++ks) {
        bfx8 a[4], b[4];
#pragma unroll
        for (int mt = 0; mt < 4; ++mt) {
            int row = wr * 64 + mt * 16 + lr;
            a[mt] = *(const bfx8*)&h2[row * 128 + swz(row, ks * 32 + lq * 8)];
        }
#pragma unroll
        for (int nt = 0; nt < 4; ++nt) {
            int n = wc * 64 + nt * 16 + lr;
            b[nt] = *(const bfx8*)(spw3t + n * 128 + ks * 32 + lq * 8);
        }
#pragma unroll
        for (int mt = 0; mt < 4; ++mt)
#pragma unroll
            for (int nt = 0; nt < 4; ++nt)
                acc2[mt][nt] = mfma16(a[mt], b[nt], acc2[mt][nt]);
    }
#pragma unroll
    for (int mt = 0; mt < 4; ++mt)
#pragma unroll
        for (int nt = 0; nt < 4; ++nt)
#pragma unroll
            for (int j = 0; j < 4; ++j) {
                int row = wr * 64 + mt * 16 + lq * 4 + j;
                int col = wc * 64 + nt * 16 + lr;
                v[(size_t)(r0 + row) * 128 + col] = f2bf(acc2[mt][nt][j] + spb3[col]);
            }
}

// ---------- K2: joined = [pib | v] @ WcT; vp-tail fused on n0==512 blocks ----------
// all-bf16 reg-staged prefetch (R7 structure: VGPR ~104, 4 blocks/CU)
__global__ __launch_bounds__(256) void k_join(
    const unsigned short* pib, const unsigned short* v, const unsigned short* wct,
    const float* joinb, const float* vpb1,
    const unsigned short* vpw2t, const unsigned short* vpw3t,
    const float* vpb2, const float* vpb3,
    unsigned short* joined, float* out_vp)
{
    __shared__ alignas(16) unsigned short stg[16384];   // At [0,8192) | Bt [8192,16384)
    int d = blockIdx.x;
    int L = (d & 7) * 160 + (d >> 3);       // XCD swizzle (1280 % 8 == 0, bijective)
    int m0 = (L / 5) * 128, n0 = (L % 5) * 128;
    int tid = threadIdx.x, wave = tid >> 6, lane = tid & 63, lq = lane >> 4, lr = lane & 15;
    int wr = wave >> 1, wc = wave & 1;

    int r0t = tid >> 3, s0t = tid & 7;
    int ss = s0t ^ (r0t & 7);
    const unsigned short* pA = pib + (size_t)(m0 + r0t) * 512 + s0t * 8;
    const unsigned short* pAv = v + (size_t)(m0 + r0t) * 128 + s0t * 8;
    const unsigned short* pB = wct + (size_t)(n0 + r0t) * 640 + s0t * 8;
    unsigned short* lA = &stg[r0t * 64 + ss * 8];
    unsigned short* lB = &stg[8192 + r0t * 64 + ss * 8];

    uint4v ra[4], rb[4];
#pragma unroll
    for (int c2 = 0; c2 < 4; ++c2) {        // prologue: chunk 0
        ra[c2] = *(const uint4v*)(pA + c2 * 16384);
        rb[c2] = *(const uint4v*)(pB + c2 * 20480);
    }
    f32x4 acc[4][4] = {};
#pragma unroll 1
    for (int kt = 0; kt < 10; ++kt) {
#pragma unroll
        for (int c2 = 0; c2 < 4; ++c2) {
            *(uint4v*)(lA + c2 * 2048) = ra[c2];
            *(uint4v*)(lB + c2 * 2048) = rb[c2];
        }
        __syncthreads();
        if (kt < 9) {                        // prefetch kt+1; latency hides under MFMA
            if (kt < 7) {
#pragma unroll
                for (int c2 = 0; c2 < 4; ++c2)
                    ra[c2] = *(const uint4v*)(pA + c2 * 16384 + (kt + 1) * 64);
            } else {
#pragma unroll
                for (int c2 = 0; c2 < 4; ++c2)
                    ra[c2] = *(const uint4v*)(pAv + c2 * 4096 + (kt + 1 - 8) * 64);
            }
#pragma unroll
            for (int c2 = 0; c2 < 4; ++c2)
                rb[c2] = *(const uint4v*)(pB + c2 * 20480 + (kt + 1) * 64);
        }
#pragma unroll
        for (int ks = 0; ks < 2; ++ks) {
            bfx8 a[4], b[4];
#pragma unroll
            for (int mt = 0; mt < 4; ++mt) {
                int row = wr * 64 + mt * 16 + lr;
                a[mt] = *(const bfx8*)&stg[row * 64 + ((ks * 32 + lq * 8) ^ ((row & 7) << 3))];
            }
#pragma unroll
            for (int nt = 0; nt < 4; ++nt) {
                int n = wc * 64 + nt * 16 + lr;
                b[nt] = *(const bfx8*)&stg[8192 + n * 64 + ((ks * 32 + lq * 8) ^ ((n & 7) << 3))];
            }
#pragma unroll
            for (int mt = 0; mt < 4; ++mt)
#pragma unroll
                for (int nt = 0; nt < 4; ++nt)
                    acc[mt][nt] = mfma16(a[mt], b[nt], acc[mt][nt]);
        }
        __syncthreads();
    }

    if (n0 < 512) {
#pragma unroll
        for (int mt = 0; mt < 4; ++mt)
#pragma unroll
            for (int nt = 0; nt < 4; ++nt)
#pragma unroll
                for (int j = 0; j < 4; ++j) {
                    int row = m0 + wr * 64 + mt * 16 + lq * 4 + j;
                    int col = n0 + wc * 64 + nt * 16 + lr;
                    joined[(size_t)row * 512 + col] = f2bf(acc[mt][nt][j] + joinb[col]);
                }
        return;
    }

    // ---- n0==512: g1 = relu(acc + vpb1) -> fused vp tail ----
#pragma unroll
    for (int mt = 0; mt < 4; ++mt)
#pragma unroll
        for (int nt = 0; nt < 4; ++nt)
#pragma unroll
            for (int j = 0; j < 4; ++j) {
                int row = wr * 64 + mt * 16 + lq * 4 + j;
                int col = wc * 64 + nt * 16 + lr;
                float x = acc[mt][nt][j] + vpb1[col];
                x = x > 0.f ? x : 0.f;
                stg[row * 128 + swz(row, col)] = f2bf(x);
            }
    __syncthreads();
    f32x4 acc2[4][4] = {};
#pragma unroll
    for (int ks = 0; ks < 4; ++ks) {
        bfx8 a[4], b[4];
#pragma unroll
        for (int mt = 0; mt < 4; ++mt) {
            int row = wr * 64 + mt * 16 + lr;
            a[mt] = *(const bfx8*)&stg[row * 128 + swz(row, ks * 32 + lq * 8)];
        }
#pragma unroll
        for (int nt = 0; nt < 4; ++nt) {
            int n = wc * 64 + nt * 16 + lr;
            b[nt] = *(const bfx8*)(vpw2t + n * 128 + ks * 32 + lq * 8);
        }
#pragma unroll
        for (int mt = 0; mt < 4; ++mt)
#pragma unroll
            for (int nt = 0; nt < 4; ++nt)
                acc2[mt][nt] = mfma16(a[mt], b[nt], acc2[mt][nt]);
    }
    __syncthreads();
#pragma unroll
    for (int mt = 0; mt < 4; ++mt)
#pragma unroll
        for (int nt = 0; nt < 4; ++nt)
#pragma unroll
            for (int j = 0; j < 4; ++j) {
                int row = wr * 64 + mt * 16 + lq * 4 + j;
                int col = wc * 64 + nt * 16 + lr;
                float x = acc2[mt][nt][j] + vpb2[col];
                x = x > 0.f ? x : 0.f;
                stg[row * 128 + swz(row, col)] = f2bf(x);
            }
    __syncthreads();
    f32x4 acc3[2] = {};
#pragma unroll
    for (int ks = 0; ks < 4; ++ks) {
        bfx8 b = *(const bfx8*)(vpw3t + lr * 128 + ks * 32 + lq * 8);
#pragma unroll
        for (int mt = 0; mt < 2; ++mt) {
            int row = wave * 32 + mt * 16 + lr;
            bfx8 a = *(const bfx8*)&stg[row * 128 + swz(row, ks * 32 + lq * 8)];
            acc3[mt] = mfma16(a, b, acc3[mt]);
        }
    }
    if (lr == 0) {
#pragma unroll
        for (int mt = 0; mt < 2; ++mt)
#pragma unroll
            for (int j = 0; j < 4; ++j) {
                int row = wave * 32 + mt * 16 + lq * 4 + j;
                out_vp[m0 + row] = acc3[mt][j] + vpb3[0];
            }
    }
}

// ---------- K3: routed control heads; staging via global_load_lds (pre-swizzled source) ----------
__global__ __launch_bounds__(512) void k_ctrl(
    const unsigned short* joined, const unsigned short* c1t, const unsigned short* c2t,
    const unsigned short* c3t, const float* b1, const float* b2, const float* b3,
    const int* cnt, const int* sorted, float* out_act)
{
    __shared__ alignas(16) unsigned short hls[128 * 256];  // h, then h2 (swizzled)
    __shared__ alignas(16) unsigned short Ast[128 * 64];   // A K-chunk (source-swizzled)
    __shared__ alignas(16) unsigned short Bst[256 * 64];   // W K-chunk (source-swizzled)
    __shared__ int ridx[128];
    int bid = blockIdx.x;
    int e = bid >> 8, i = bid & 255;
    int n_e = cnt[e];
    if (i * 128 >= n_e) return;
    int tid = threadIdx.x;
    if (tid < 128) {
        int g = i * 128 + tid;
        ridx[tid] = sorted[e * NROWS + (g < n_e ? g : n_e - 1)];
    }
    __syncthreads();
    int wave = tid >> 6, lane = tid & 63, lq = lane >> 4, lr = lane & 15;
    int wm = wave & 1, wn = wave >> 1;        // 2 M-waves x 4 N-waves
    const unsigned short* W1 = c1t + e * (256 * 512);
    const unsigned short* W2 = c2t + e * (256 * 256);
    const unsigned short* W3 = c3t + e * (16 * 256);

    // ---- GEMM1: h = relu(A @ W1T + b1), K=512 in 8 chunks of 64 ----
    f32x4 acc[4][4] = {};
#pragma unroll 1
    for (int kt = 0; kt < 8; ++kt) {
        // A: 1024 16B-chunks, linear LDS dest, pre-swizzled gathered source
#pragma unroll
        for (int it = 0; it < 2; ++it) {
            int chunk = it * 512 + tid;
            int row = chunk >> 3, sl = (chunk & 7) ^ (row & 7);
            gload_lds16(joined + (size_t)ridx[row] * 512 + kt * 64 + sl * 8,
                        &Ast[(it * 512 + wave * 64) * 8]);
        }
        // B: 2048 16B-chunks
#pragma unroll
        for (int it = 0; it < 4; ++it) {
            int chunk = it * 512 + tid;
            int n = chunk >> 3, sl = (chunk & 7) ^ (n & 7);
            gload_lds16(W1 + (size_t)n * 512 + kt * 64 + sl * 8,
                        &Bst[(it * 512 + wave * 64) * 8]);
        }
        __syncthreads();
#pragma unroll
        for (int ks = 0; ks < 2; ++ks) {
            bfx8 a[4], b[4];
#pragma unroll
            for (int mt = 0; mt < 4; ++mt) {
                int row = wm * 64 + mt * 16 + lr;
                a[mt] = *(const bfx8*)&Ast[row * 64 + ((ks * 32 + lq * 8) ^ ((row & 7) << 3))];
            }
#pragma unroll
            for (int nt = 0; nt < 4; ++nt) {
                int n = wn * 64 + nt * 16 + lr;
                b[nt] = *(const bfx8*)&Bst[n * 64 + ((ks * 32 + lq * 8) ^ ((n & 7) << 3))];
            }
#pragma unroll
            for (int mt = 0; mt < 4; ++mt)
#pragma unroll
                for (int nt = 0; nt < 4; ++nt)
                    acc[mt][nt] = mfma16(a[mt], b[nt], acc[mt][nt]);
        }
        __syncthreads();
    }
#pragma unroll
    for (int mt = 0; mt < 4; ++mt)
#pragma unroll
        for (int nt = 0; nt < 4; ++nt)
#pragma unroll
            for (int j = 0; j < 4; ++j) {
                int row = wm * 64 + mt * 16 + lq * 4 + j;
                int col = wn * 64 + nt * 16 + lr;
                float x = acc[mt][nt][j] + b1[e * 256 + col];
                x = x > 0.f ? x : 0.f;
                hls[row * 256 + swz(row, col)] = f2bf(x);
            }
    __syncthreads();

    // ---- GEMM2: h2 = relu(h @ W2T + b2), K=256 in 4 chunks of 64 ----
    f32x4 acc2[4][4] = {};
#pragma unroll 1
    for (int kt = 0; kt < 4; ++kt) {
#pragma unroll
        for (int it = 0; it < 4; ++it) {
            int chunk = it * 512 + tid;
            int n = chunk >> 3, sl = (chunk & 7) ^ (n & 7);
            gload_lds16(W2 + (size_t)n * 256 + kt * 64 + sl * 8,
                        &Bst[(it * 512 + wave * 64) * 8]);
        }
        __syncthreads();
#pragma unroll
        for (int ks = 0; ks < 2; ++ks) {
            bfx8 a[4], b[4];
#pragma unroll
            for (int mt = 0; mt < 4; ++mt) {
                int row = wm * 64 + mt * 16 + lr;
                a[mt] = *(const bfx8*)&hls[row * 256 + swz(row, kt * 64 + ks * 32 + lq * 8)];
            }
#pragma unroll
            for (int nt = 0; nt < 4; ++nt) {
                int n = wn * 64 + nt * 16 + lr;
                b[nt] = *(const bfx8*)&Bst[n * 64 + ((ks * 32 + lq * 8) ^ ((n & 7) << 3))];
            }
#pragma unroll
            for (int mt = 0; mt < 4; ++mt)
#pragma unroll
                for (int nt = 0; nt < 4; ++nt)
                    acc2[mt][nt] = mfma16(a[mt], b[nt], acc2[mt][nt]);
        }
        __syncthreads();
    }
#pragma unroll
    for (int mt = 0; mt < 4; ++mt)
#pragma unroll
        for (int nt = 0; nt < 4; ++nt)
#pragma unroll
            for (int j = 0; j < 4; ++j) {
                int row = wm * 64 + mt * 16 + lq * 4 + j;
                int col = wn * 64 + nt * 16 + lr;
                float x = acc2[mt][nt][j] + b2[e * 256 + col];
                x = x > 0.f ? x : 0.f;
                hls[row * 256 + swz(row, col)] = f2bf(x);
            }
    __syncthreads();

    // ---- GEMM3: a = h2 @ W3T(pad N=16) + b3; each wave owns 16 rows; cols 0..2 valid ----
    {
        f32x4 acc3 = {};
#pragma unroll
        for (int ks = 0; ks < 8; ++ks) {
            int row = wave * 16 + lr;
            bfx8 a = *(const bfx8*)&hls[row * 256 + swz(row, ks * 32 + lq * 8)];
            bfx8 b = *(const bfx8*)(W3 + lr * 256 + ks * 32 + lq * 8);
            acc3 = mfma16(a, b, acc3);
        }
#pragma unroll
        for (int j = 0; j < 4; ++j) {
            int row = wave * 16 + lq * 4 + j;
            int g = i * 128 + row;
            if (lr < 3 && g < n_e)
                out_act[(size_t)ridx[row] * 3 + lr] = acc3[j] + b3[e * 3 + lr];
        }
    }
}

// ---------- launch ----------
extern "C" void kernel_launch(void* const* d_in, const int* in_sizes, int n_in,
                              void* d_out, int out_size, void* d_ws, size_t ws_size,
                              hipStream_t stream) {
    (void)in_sizes; (void)n_in; (void)out_size;
    if (ws_size < WS_NEED) return;

    const float* p_i    = (const float*)d_in[0];
    const float* speed  = (const float*)d_in[1];
    const int*   command= (const int*)d_in[2];
    const float* sp_W1  = (const float*)d_in[3];
    const float* sp_b1  = (const float*)d_in[4];
    const float* sp_W2  = (const float*)d_in[5];
    const float* sp_b2  = (const float*)d_in[6];
    const float* sp_W3  = (const float*)d_in[7];
    const float* sp_b3  = (const float*)d_in[8];
    const float* vp_W1  = (const float*)d_in[9];
    const float* vp_b1  = (const float*)d_in[10];
    const float* vp_W2  = (const float*)d_in[11];
    const float* vp_b2  = (const float*)d_in[12];
    const float* vp_W3  = (const float*)d_in[13];
    const float* vp_b3  = (const float*)d_in[14];
    const float* join_W = (const float*)d_in[15];
    const float* join_b = (const float*)d_in[16];
    const float* ctrl_W1= (const float*)d_in[17];
    const float* ctrl_b1= (const float*)d_in[18];
    const float* ctrl_W2= (const float*)d_in[19];
    const float* ctrl_b2= (const float*)d_in[20];
    const float* ctrl_W3= (const float*)d_in[21];
    const float* ctrl_b3= (const float*)d_in[22];

    char* ws = (char*)d_ws;
    unsigned short* joined = (unsigned short*)(ws + JOINED_B);
    unsigned short* pib    = (unsigned short*)(ws + PI_B);
    unsigned short* vbuf   = (unsigned short*)(ws + V_B);
    unsigned short* wct    = (unsigned short*)(ws + WCT_B);
    unsigned short* spw2t  = (unsigned short*)(ws + SPW2T_B);
    unsigned short* spw3t  = (unsigned short*)(ws + SPW3T_B);
    unsigned short* vpw2t  = (unsigned short*)(ws + VPW2T_B);
    unsigned short* vpw3t  = (unsigned short*)(ws + VPW3T_B);
    unsigned short* c1t    = (unsigned short*)(ws + C1T_B);
    unsigned short* c2t    = (unsigned short*)(ws + C2T_B);
    unsigned short* c3t    = (unsigned short*)(ws + C3T_B);
    int* cnt    = (int*)(ws + CNT_B);
    int* sorted = (int*)(ws + SORTED_B);

    float* out_vp  = (float*)d_out;          // output dtype FLOAT32
    float* out_act = out_vp + NROWS;

    k_prep<<<5266, 256, 0, stream>>>(p_i, join_W, vp_W1, sp_W2, sp_W3, vp_W2, vp_W3,
                                     ctrl_W1, ctrl_W2, ctrl_W3,
                                     pib, wct, spw2t, spw3t, vpw2t, vpw3t,
                                     c1t, c2t, c3t, cnt);
    k_sp<<<256, 256, 0, stream>>>(speed, sp_W1, sp_b1, sp_b2, sp_b3,
                                  spw2t, spw3t, command, cnt, sorted, vbuf);
    k_join<<<1280, 256, 0, stream>>>(pib, vbuf, wct, join_b, vp_b1,
                                     vpw2t, vpw3t, vp_b2, vp_b3, joined, out_vp);
    k_ctrl<<<1024, 512, 0, stream>>>(joined, c1t, c2t, c3t, ctrl_b1, ctrl_b2, ctrl_b3,
                                     cnt, sorted, out_act);
}

// Round 11
// 257.913 us; speedup vs baseline: 1.6189x; 1.0631x over previous
//
#include <hip/hip_runtime.h>
#include <stdint.h>

#define NROWS 32768
#define BW1S 245760   // 384*640 per expert

typedef float f32x4 __attribute__((ext_vector_type(4)));
typedef __bf16 bfx8 __attribute__((ext_vector_type(8)));
typedef unsigned uint4v __attribute__((ext_vector_type(4)));

// ---------- helpers ----------
static __device__ __forceinline__ unsigned short f2bf(float f) {
    unsigned u = __builtin_bit_cast(unsigned, f);
    u += 0x7fffu + ((u >> 16) & 1u);   // RNE
    return (unsigned short)(u >> 16);
}

static __device__ __forceinline__ f32x4 mfma16(bfx8 a, bfx8 b, f32x4 c) {
    return __builtin_amdgcn_mfma_f32_16x16x32_bf16(a, b, c, 0, 0, 0);
}

// XOR swizzle of column index (elements, bf16): permutes 16B slots within 8-slot groups
static __device__ __forceinline__ int swz(int row, int col) {
    return col ^ ((row & 7) << 3);
}

// ---------- workspace layout (bytes) ----------
static constexpr size_t PI_B     = 0;            // [32768][512] bf16 = 33,554,432
static constexpr size_t V_B      = 33554432;     // [32768][128] bf16 =  8,388,608
static constexpr size_t JOINWB_B = 41943040;     // [640][512] bf16   =    655,360
static constexpr size_t C1T_B    = 42598400;     // [4][256][512] bf16=  1,048,576
static constexpr size_t C2T_B    = 43646976;     // [4][256][256] bf16=    524,288
static constexpr size_t C3T_B    = 44171264;     // [4][16][256] bf16 =     32,768
static constexpr size_t SPW2T_B  = 44204032;     // [128][128] bf16
static constexpr size_t SPW3T_B  = 44236800;
static constexpr size_t VPW2T_B  = 44269568;
static constexpr size_t VPW3T_B  = 44302336;     // [16][128] bf16
static constexpr size_t BW1_B    = 44306432;     // [4][384][640] bf16= 1,966,080
static constexpr size_t B1P_B    = 46272512;     // [4][256] f32      =      4,096
static constexpr size_t CNT_B    = 46276608;     // 16 ints
static constexpr size_t SORTED_B = 46276672;     // [4][32768] int    =    524,288
static constexpr size_t WS_NEED  = 46800960;

// ---------- K0: pib conversion + all weight layout transforms ----------
__global__ __launch_bounds__(256) void k_prep(
    const float* p_i, const float* joinW, const float* vpW1,
    const float* spW2, const float* spW3, const float* vpW2, const float* vpW3,
    const float* c1, const float* c2, const float* c3,
    unsigned short* pib, unsigned short* joinWb, unsigned short* c1t,
    unsigned short* c2t, unsigned short* c3t,
    unsigned short* spw2t, unsigned short* spw3t, unsigned short* vpw2t,
    unsigned short* vpw3t, unsigned short* bw1, int* cnt)
{
    int bid = blockIdx.x, tid = threadIdx.x;
    if (bid == 0 && tid < 16) cnt[tid] = 0;
    if (bid < 4096) {
        size_t c0 = (size_t)bid * 1024;   // p_i f32->bf16, coalesced both sides
#pragma unroll
        for (int j = 0; j < 4; ++j) {
            size_t c = c0 + tid + j * 256;
            f32x4 x = *(const f32x4*)(p_i + c * 4);
            ushort4 o;
            o.x = f2bf(x[0]); o.y = f2bf(x[1]); o.z = f2bf(x[2]); o.w = f2bf(x[3]);
            *(ushort4*)(pib + c * 4) = o;
        }
        return;
    }
    int b = bid - 4096;
    int region, s0;
    if      (b < 320)  { region = 0; s0 = b * 1024; }            // joinWb elementwise
    else if (b < 832)  { region = 1; s0 = (b - 320) * 1024; }    // c1t
    else if (b < 1088) { region = 2; s0 = (b - 832) * 1024; }    // c2t
    else if (b < 1104) { region = 3; s0 = (b - 1088) * 1024; }   // c3t
    else if (b < 1120) { region = 4; s0 = (b - 1104) * 1024; }   // spw2t
    else if (b < 1136) { region = 5; s0 = (b - 1120) * 1024; }   // spw3t
    else if (b < 1152) { region = 6; s0 = (b - 1136) * 1024; }   // vpw2t
    else if (b < 1154) { region = 7; s0 = (b - 1152) * 1024; }   // vpw3t
    else if (b < 1218) { region = 8; s0 = (b - 1154) * 1024; }   // bw1 vp-rows copy
    else               { region = 9; s0 = (b - 1218) * 1024; }   // bw1 vp-rows zero pad
    for (int j = 0; j < 4; ++j) {
        int s = s0 + tid + j * 256;
        switch (region) {
        case 0: joinWb[s] = f2bf(joinW[s]); break;               // [640 k][512 n] natural
        case 1: { int e = s >> 17, n = (s >> 8) & 511, m = s & 255;
                  c1t[e * 131072 + m * 512 + n] = f2bf(c1[s]); } break;
        case 2: { int e = s >> 16, k = (s >> 8) & 255, n = s & 255;
                  c2t[e * 65536 + n * 256 + k] = f2bf(c2[s]); } break;
        case 3: { int e = s >> 12, r = s & 4095, n = r >> 8, k = r & 255;
                  c3t[s] = (n < 3) ? f2bf(c3[e * 768 + k * 3 + n]) : 0; } break;
        case 4: { int k = s >> 7, n = s & 127; spw2t[n * 128 + k] = f2bf(spW2[s]); } break;
        case 5: { int k = s >> 7, n = s & 127; spw3t[n * 128 + k] = f2bf(spW3[s]); } break;
        case 6: { int k = s >> 7, n = s & 127; vpw2t[n * 128 + k] = f2bf(vpW2[s]); } break;
        case 7: { vpw3t[s] = (s < 128) ? f2bf(vpW3[s]) : 0; } break;
        case 8: { int k = s >> 7, n = s & 127;
                  unsigned short val = f2bf(vpW1[s]);
#pragma unroll
                  for (int e = 0; e < 4; ++e)
                      bw1[e * BW1S + (256 + n) * 640 + k] = val;
                } break;
        case 9: { int n = s >> 7, k = 512 + (s & 127);
#pragma unroll
                  for (int e = 0; e < 4; ++e)
                      bw1[e * BW1S + (256 + n) * 640 + k] = 0;
                } break;
        }
    }
}

// ---------- K1: sp-MLP + scatter (blocks 0-255) | W1 fold GEMM (256-295) | b1p (296-299) ----------
__global__ __launch_bounds__(256) void k_sp(
    const float* speed, const float* spW1, const float* spb1,
    const float* spb2, const float* spb3,
    const unsigned short* spw2t, const unsigned short* spw3t,
    const int* command, int* cnt, int* sorted, unsigned short* v,
    const unsigned short* c1t, const unsigned short* joinWb, unsigned short* bw1,
    const float* c1f, const float* jb, const float* b1f, float* b1p)
{
    __shared__ alignas(16) unsigned short h1[128 * 128];
    __shared__ alignas(16) unsigned short h2[128 * 128];
    __shared__ int lcnt[4], lbase[4];
    int bid = blockIdx.x, tid = threadIdx.x;

    if (bid >= 296) {         // ---- b1p[e] = b1 + join_b @ W1e (f32 exact) ----
        int e = bid - 296;
        float a = b1f[e * 256 + tid];
        for (int n = 0; n < 512; ++n)
            a = fmaf(jb[n], c1f[(size_t)e * 131072 + n * 256 + tid], a);
        b1p[e * 256 + tid] = a;
        return;
    }
    if (bid >= 256) {         // ---- fold: bw1[e][m][k] = sum_n c1t[e][m][n] * joinWb[k][n] ----
        int fid = bid - 256;
        int e = fid / 10, rem = fid % 10;
        int m0 = (rem / 5) * 128, k0 = (rem % 5) * 128;
        const unsigned short* A = c1t + e * 131072;      // [256 m][512 n]
        unsigned short* stA = h1;                        // [128][64] swizzled
        unsigned short* stB = h1 + 8192;
        int wave = tid >> 6, lane = tid & 63, lq = lane >> 4, lr = lane & 15;
        int wr = wave >> 1, wc = wave & 1;
        f32x4 acc[4][4] = {};
#pragma unroll 1
        for (int kt = 0; kt < 8; ++kt) {
#pragma unroll
            for (int it = 0; it < 4; ++it) {
                int chunk = it * 256 + tid;              // 1024 chunks of 16B
                int row = chunk >> 3, sl = chunk & 7;
                uint4v va = *(const uint4v*)(A + (size_t)(m0 + row) * 512 + kt * 64 + sl * 8);
                uint4v vb = *(const uint4v*)(joinWb + (size_t)(k0 + row) * 512 + kt * 64 + sl * 8);
                *(uint4v*)&stA[row * 64 + (sl ^ (row & 7)) * 8] = va;
                *(uint4v*)&stB[row * 64 + (sl ^ (row & 7)) * 8] = vb;
            }
            __syncthreads();
#pragma unroll
            for (int ks = 0; ks < 2; ++ks) {
                bfx8 a[4], bb[4];
#pragma unroll
                for (int mt = 0; mt < 4; ++mt) {
                    int row = wr * 64 + mt * 16 + lr;
                    a[mt] = *(const bfx8*)&stA[row * 64 + ((ks * 32 + lq * 8) ^ ((row & 7) << 3))];
                }
#pragma unroll
                for (int nt = 0; nt < 4; ++nt) {
                    int n = wc * 64 + nt * 16 + lr;
                    bb[nt] = *(const bfx8*)&stB[n * 64 + ((ks * 32 + lq * 8) ^ ((n & 7) << 3))];
                }
#pragma unroll
                for (int mt = 0; mt < 4; ++mt)
#pragma unroll
                    for (int nt = 0; nt < 4; ++nt)
                        acc[mt][nt] = mfma16(a[mt], bb[nt], acc[mt][nt]);
            }
            __syncthreads();
        }
#pragma unroll
        for (int mt = 0; mt < 4; ++mt)
#pragma unroll
            for (int nt = 0; nt < 4; ++nt)
#pragma unroll
                for (int j = 0; j < 4; ++j) {
                    int m = wr * 64 + mt * 16 + lq * 4 + j;
                    int k = wc * 64 + nt * 16 + lr;
                    bw1[e * BW1S + (m0 + m) * 640 + k0 + k] = f2bf(acc[mt][nt][j]);
                }
        return;
    }

    // ---- sp-MLP + scatter ----
    int r0 = bid * 128;
    if (tid < 4) lcnt[tid] = 0;
    __syncthreads();
    int cc = 0, lpos = 0;
    if (tid < 128) { cc = command[r0 + tid] & 3; lpos = atomicAdd(&lcnt[cc], 1); }
    __syncthreads();
    if (tid < 4) lbase[tid] = atomicAdd(&cnt[tid], lcnt[tid]);
    __syncthreads();
    if (tid < 128) sorted[cc * NROWS + lbase[cc] + lpos] = r0 + tid;

    for (int j = 0; j < 64; ++j) {
        int idx = tid + j * 256;
        int row = idx >> 7, col = idx & 127;
        float h = speed[r0 + row] * spW1[col] + spb1[col];
        h = h > 0.f ? h : 0.f;
        h1[row * 128 + swz(row, col)] = f2bf(h);
    }
    __syncthreads();

    int wave = tid >> 6, lane = tid & 63, lq = lane >> 4, lr = lane & 15;
    int wr = wave >> 1, wc = wave & 1;
    f32x4 acc[4][4] = {};
#pragma unroll
    for (int ks = 0; ks < 4; ++ks) {
        bfx8 a[4], b[4];
#pragma unroll
        for (int mt = 0; mt < 4; ++mt) {
            int row = wr * 64 + mt * 16 + lr;
            a[mt] = *(const bfx8*)&h1[row * 128 + swz(row, ks * 32 + lq * 8)];
        }
#pragma unroll
        for (int nt = 0; nt < 4; ++nt) {
            int n = wc * 64 + nt * 16 + lr;
            b[nt] = *(const bfx8*)(spw2t + n * 128 + ks * 32 + lq * 8);
        }
#pragma unroll
        for (int mt = 0; mt < 4; ++mt)
#pragma unroll
            for (int nt = 0; nt < 4; ++nt)
                acc[mt][nt] = mfma16(a[mt], b[nt], acc[mt][nt]);
    }
#pragma unroll
    for (int mt = 0; mt < 4; ++mt)
#pragma unroll
        for (int nt = 0; nt < 4; ++nt)
#pragma unroll
            for (int j = 0; j < 4; ++j) {
                int row = wr * 64 + mt * 16 + lq * 4 + j;
                int col = wc * 64 + nt * 16 + lr;
                float x = acc[mt][nt][j] + spb2[col];
                x = x > 0.f ? x : 0.f;
                h2[row * 128 + swz(row, col)] = f2bf(x);
            }
    __syncthreads();
    f32x4 acc2[4][4] = {};
#pragma unroll
    for (int ks = 0; ks < 4; ++ks) {
        bfx8 a[4], b[4];
#pragma unroll
        for (int mt = 0; mt < 4; ++mt) {
            int row = wr * 64 + mt * 16 + lr;
            a[mt] = *(const bfx8*)&h2[row * 128 + swz(row, ks * 32 + lq * 8)];
        }
#pragma unroll
        for (int nt = 0; nt < 4; ++nt) {
            int n = wc * 64 + nt * 16 + lr;
            b[nt] = *(const bfx8*)(spw3t + n * 128 + ks * 32 + lq * 8);
        }
#pragma unroll
        for (int mt = 0; mt < 4; ++mt)
#pragma unroll
            for (int nt = 0; nt < 4; ++nt)
                acc2[mt][nt] = mfma16(a[mt], b[nt], acc2[mt][nt]);
    }
#pragma unroll
    for (int mt = 0; mt < 4; ++mt)
#pragma unroll
        for (int nt = 0; nt < 4; ++nt)
#pragma unroll
            for (int j = 0; j < 4; ++j) {
                int row = wr * 64 + mt * 16 + lq * 4 + j;
                int col = wc * 64 + nt * 16 + lr;
                v[(size_t)(r0 + row) * 128 + col] = f2bf(acc2[mt][nt][j] + spb3[col]);
            }
}

// ---------- K2: mega ctrl+vp. A = gathered [pib|v] rows (K=640). ----------
// GEMM1 N=384 = [ctrl W1' (256) | vpW1_pad (128)], then ctrl GEMM2/3 + vp tail.
// LDS 128KB region reuse: GEMM1 staging [0,64KB) -> h [0,64KB), g1 [64,96KB), stage2/g2 [96,128KB)
__global__ __launch_bounds__(512) void k_ctrl(
    const unsigned short* pib, const unsigned short* v,
    const unsigned short* bw1, const float* b1p,
    const unsigned short* c2t, const unsigned short* c3t,
    const unsigned short* vpw2t, const unsigned short* vpw3t,
    const float* b2, const float* b3,
    const float* vpb1, const float* vpb2, const float* vpb3,
    const int* cnt, const int* sorted, float* out_vp, float* out_act)
{
    __shared__ alignas(16) unsigned short lds[65536];   // 128 KB
    __shared__ int ridx[128];
    const int AST = 0, BST = 8192;          // GEMM1 staging (shorts)
    const int H = 0, G1 = 32768, WS = 49152;
    int bid = blockIdx.x;
    int e = bid >> 8, i = bid & 255;
    int n_e = cnt[e];
    if (i * 128 >= n_e) return;
    int tid = threadIdx.x;
    if (tid < 128) {
        int g = i * 128 + tid;
        ridx[tid] = sorted[e * NROWS + (g < n_e ? g : n_e - 1)];
    }
    __syncthreads();
    int wave = tid >> 6, lane = tid & 63, lq = lane >> 4, lr = lane & 15;
    int wm = wave & 1, wn = wave >> 1;      // 2 M-waves x 4 N-waves
    const unsigned short* BW = bw1 + e * BW1S;

    // ---- GEMM1: [128 rows] x [384 n], K=640 in 10 chunks of 64 ----
    f32x4 acc[4][6] = {};
#pragma unroll 1
    for (int kt = 0; kt < 10; ++kt) {
        // A [128][64]: 1024 chunks
#pragma unroll
        for (int it = 0; it < 2; ++it) {
            int chunk = it * 512 + tid;
            int row = chunk >> 3, sl = chunk & 7;
            uint4v val;
            if (kt < 8) val = *(const uint4v*)(pib + (size_t)ridx[row] * 512 + kt * 64 + sl * 8);
            else        val = *(const uint4v*)(v + (size_t)ridx[row] * 128 + (kt - 8) * 64 + sl * 8);
            *(uint4v*)&lds[AST + row * 64 + (sl ^ (row & 7)) * 8] = val;
        }
        // B [384][64]: 3072 chunks
#pragma unroll
        for (int it = 0; it < 6; ++it) {
            int chunk = it * 512 + tid;
            int n = chunk >> 3, sl = chunk & 7;
            uint4v val = *(const uint4v*)(BW + (size_t)n * 640 + kt * 64 + sl * 8);
            *(uint4v*)&lds[BST + n * 64 + (sl ^ (n & 7)) * 8] = val;
        }
        __syncthreads();
#pragma unroll
        for (int ks = 0; ks < 2; ++ks) {
            bfx8 a[4], b[6];
#pragma unroll
            for (int mt = 0; mt < 4; ++mt) {
                int row = wm * 64 + mt * 16 + lr;
                a[mt] = *(const bfx8*)&lds[AST + row * 64 + ((ks * 32 + lq * 8) ^ ((row & 7) << 3))];
            }
#pragma unroll
            for (int nt = 0; nt < 6; ++nt) {
                int n = wn * 96 + nt * 16 + lr;
                b[nt] = *(const bfx8*)&lds[BST + n * 64 + ((ks * 32 + lq * 8) ^ ((n & 7) << 3))];
            }
#pragma unroll
            for (int mt = 0; mt < 4; ++mt)
#pragma unroll
                for (int nt = 0; nt < 6; ++nt)
                    acc[mt][nt] = mfma16(a[mt], b[nt], acc[mt][nt]);
        }
        __syncthreads();
    }
    // epilogue: h (cols 0-255) -> H, g1 (cols 256-383) -> G1
#pragma unroll
    for (int mt = 0; mt < 4; ++mt)
#pragma unroll
        for (int nt = 0; nt < 6; ++nt)
#pragma unroll
            for (int j = 0; j < 4; ++j) {
                int row = wm * 64 + mt * 16 + lq * 4 + j;
                int col = wn * 96 + nt * 16 + lr;
                float x = acc[mt][nt][j];
                if (col < 256) {
                    x += b1p[e * 256 + col];
                    x = x > 0.f ? x : 0.f;
                    lds[H + row * 256 + swz(row, col)] = f2bf(x);
                } else {
                    x += vpb1[col - 256];
                    x = x > 0.f ? x : 0.f;
                    lds[G1 + row * 128 + swz(row, col - 256)] = f2bf(x);
                }
            }
    __syncthreads();

    // ---- ctrl GEMM2: h2 = relu(h @ W2T + b2), K=256 in 4 chunks; W2 staged in WS ----
    f32x4 acc2[4][4] = {};
    const unsigned short* W2 = c2t + e * 65536;
#pragma unroll 1
    for (int kt = 0; kt < 4; ++kt) {
#pragma unroll
        for (int it = 0; it < 4; ++it) {     // 2048 chunks: full 256 rows (R10 bug was it<2)
            int chunk = it * 512 + tid;
            int n = chunk >> 3, sl = chunk & 7;
            uint4v val = *(const uint4v*)(W2 + (size_t)n * 256 + kt * 64 + sl * 8);
            *(uint4v*)&lds[WS + n * 64 + (sl ^ (n & 7)) * 8] = val;
        }
        __syncthreads();
#pragma unroll
        for (int ks = 0; ks < 2; ++ks) {
            bfx8 a[4], b[4];
#pragma unroll
            for (int mt = 0; mt < 4; ++mt) {
                int row = wm * 64 + mt * 16 + lr;
                a[mt] = *(const bfx8*)&lds[H + row * 256 + swz(row, kt * 64 + ks * 32 + lq * 8)];
            }
#pragma unroll
            for (int nt = 0; nt < 4; ++nt) {
                int n = wn * 64 + nt * 16 + lr;
                b[nt] = *(const bfx8*)&lds[WS + n * 64 + ((ks * 32 + lq * 8) ^ ((n & 7) << 3))];
            }
#pragma unroll
            for (int mt = 0; mt < 4; ++mt)
#pragma unroll
                for (int nt = 0; nt < 4; ++nt)
                    acc2[mt][nt] = mfma16(a[mt], b[nt], acc2[mt][nt]);
        }
        __syncthreads();
    }
    // h2 -> H (all h reads done); vp GEMM2 reads G1, B direct from L2
#pragma unroll
    for (int mt = 0; mt < 4; ++mt)
#pragma unroll
        for (int nt = 0; nt < 4; ++nt)
#pragma unroll
            for (int j = 0; j < 4; ++j) {
                int row = wm * 64 + mt * 16 + lq * 4 + j;
                int col = wn * 64 + nt * 16 + lr;
                float x = acc2[mt][nt][j] + b2[e * 256 + col];
                x = x > 0.f ? x : 0.f;
                lds[H + row * 256 + swz(row, col)] = f2bf(x);
            }
    f32x4 accv[4][2] = {};
#pragma unroll
    for (int ks = 0; ks < 4; ++ks) {    // K=128 over g1
        bfx8 a[4], b[2];
#pragma unroll
        for (int mt = 0; mt < 4; ++mt) {
            int row = wm * 64 + mt * 16 + lr;
            a[mt] = *(const bfx8*)&lds[G1 + row * 128 + swz(row, ks * 32 + lq * 8)];
        }
#pragma unroll
        for (int nt = 0; nt < 2; ++nt) {
            int n = wn * 32 + nt * 16 + lr;
            b[nt] = *(const bfx8*)(vpw2t + n * 128 + ks * 32 + lq * 8);
        }
#pragma unroll
        for (int mt = 0; mt < 4; ++mt)
#pragma unroll
            for (int nt = 0; nt < 2; ++nt)
                accv[mt][nt] = mfma16(a[mt], b[nt], accv[mt][nt]);
    }
    __syncthreads();
    // g2 -> WS
#pragma unroll
    for (int mt = 0; mt < 4; ++mt)
#pragma unroll
        for (int nt = 0; nt < 2; ++nt)
#pragma unroll
            for (int j = 0; j < 4; ++j) {
                int row = wm * 64 + mt * 16 + lq * 4 + j;
                int col = wn * 32 + nt * 16 + lr;
                float x = accv[mt][nt][j] + vpb2[col];
                x = x > 0.f ? x : 0.f;
                lds[WS + row * 128 + swz(row, col)] = f2bf(x);
            }
    __syncthreads();

    // ---- ctrl GEMM3 (K=256 over h2) + vp GEMM3 (K=128 over g2) ----
    {
        f32x4 acc3 = {};
#pragma unroll
        for (int ks = 0; ks < 8; ++ks) {
            int row = wave * 16 + lr;
            bfx8 a = *(const bfx8*)&lds[H + row * 256 + swz(row, ks * 32 + lq * 8)];
            bfx8 b = *(const bfx8*)(c3t + e * 4096 + lr * 256 + ks * 32 + lq * 8);
            acc3 = mfma16(a, b, acc3);
        }
        f32x4 acc4 = {};
#pragma unroll
        for (int ks = 0; ks < 4; ++ks) {
            int row = wave * 16 + lr;
            bfx8 a = *(const bfx8*)&lds[WS + row * 128 + swz(row, ks * 32 + lq * 8)];
            bfx8 b = *(const bfx8*)(vpw3t + lr * 128 + ks * 32 + lq * 8);
            acc4 = mfma16(a, b, acc4);
        }
#pragma unroll
        for (int j = 0; j < 4; ++j) {
            int row = wave * 16 + lq * 4 + j;
            int g = i * 128 + row;
            if (g < n_e) {
                if (lr < 3) out_act[(size_t)ridx[row] * 3 + lr] = acc3[j] + b3[e * 3 + lr];
                if (lr == 0) out_vp[ridx[row]] = acc4[j] + vpb3[0];
            }
        }
    }
}

// ---------- launch ----------
extern "C" void kernel_launch(void* const* d_in, const int* in_sizes, int n_in,
                              void* d_out, int out_size, void* d_ws, size_t ws_size,
                              hipStream_t stream) {
    (void)in_sizes; (void)n_in; (void)out_size;
    if (ws_size < WS_NEED) return;

    const float* p_i    = (const float*)d_in[0];
    const float* speed  = (const float*)d_in[1];
    const int*   command= (const int*)d_in[2];
    const float* sp_W1  = (const float*)d_in[3];
    const float* sp_b1  = (const float*)d_in[4];
    const float* sp_W2  = (const float*)d_in[5];
    const float* sp_b2  = (const float*)d_in[6];
    const float* sp_W3  = (const float*)d_in[7];
    const float* sp_b3  = (const float*)d_in[8];
    const float* vp_W1  = (const float*)d_in[9];
    const float* vp_b1  = (const float*)d_in[10];
    const float* vp_W2  = (const float*)d_in[11];
    const float* vp_b2  = (const float*)d_in[12];
    const float* vp_W3  = (const float*)d_in[13];
    const float* vp_b3  = (const float*)d_in[14];
    const float* join_W = (const float*)d_in[15];
    const float* join_b = (const float*)d_in[16];
    const float* ctrl_W1= (const float*)d_in[17];
    const float* ctrl_b1= (const float*)d_in[18];
    const float* ctrl_W2= (const float*)d_in[19];
    const float* ctrl_b2= (const float*)d_in[20];
    const float* ctrl_W3= (const float*)d_in[21];
    const float* ctrl_b3= (const float*)d_in[22];

    char* ws = (char*)d_ws;
    unsigned short* pib    = (unsigned short*)(ws + PI_B);
    unsigned short* vbuf   = (unsigned short*)(ws + V_B);
    unsigned short* joinWb = (unsigned short*)(ws + JOINWB_B);
    unsigned short* c1t    = (unsigned short*)(ws + C1T_B);
    unsigned short* c2t    = (unsigned short*)(ws + C2T_B);
    unsigned short* c3t    = (unsigned short*)(ws + C3T_B);
    unsigned short* spw2t  = (unsigned short*)(ws + SPW2T_B);
    unsigned short* spw3t  = (unsigned short*)(ws + SPW3T_B);
    unsigned short* vpw2t  = (unsigned short*)(ws + VPW2T_B);
    unsigned short* vpw3t  = (unsigned short*)(ws + VPW3T_B);
    unsigned short* bw1    = (unsigned short*)(ws + BW1_B);
    float* b1p  = (float*)(ws + B1P_B);
    int* cnt    = (int*)(ws + CNT_B);
    int* sorted = (int*)(ws + SORTED_B);

    float* out_vp  = (float*)d_out;          // output dtype FLOAT32
    float* out_act = out_vp + NROWS;

    k_prep<<<5330, 256, 0, stream>>>(p_i, join_W, vp_W1, sp_W2, sp_W3, vp_W2, vp_W3,
                                     ctrl_W1, ctrl_W2, ctrl_W3,
                                     pib, joinWb, c1t, c2t, c3t,
                                     spw2t, spw3t, vpw2t, vpw3t, bw1, cnt);
    k_sp<<<300, 256, 0, stream>>>(speed, sp_W1, sp_b1, sp_b2, sp_b3,
                                  spw2t, spw3t, command, cnt, sorted, vbuf,
                                  c1t, joinWb, bw1, ctrl_W1, join_b, ctrl_b1, b1p);
    k_ctrl<<<1024, 512, 0, stream>>>(pib, vbuf, bw1, b1p, c2t, c3t, vpw2t, vpw3t,
                                     ctrl_b2, ctrl_b3, vp_b1, vp_b2, vp_b3,
                                     cnt, sorted, out_vp, out_act);
}